// Round 10
// baseline (178.972 us; speedup 1.0000x reference)
//
#include <hip/hip_runtime.h>
#include <hip/hip_bf16.h>

// Problem constants (GCN_66649302499531)
#define NN 20000
#define NG 400
#define D_IN 128
#define H1 256
#define H2 256
#define D_OUT 128
#define NB_RANK ((NN + 255) / 256)   // 79
#define NB_PAD 80
#define WT_ELEMS (D_IN * H1 + H1 * H2 + H2 * D_OUT)   // 131072

typedef __attribute__((ext_vector_type(8))) short short8;
typedef __attribute__((ext_vector_type(4))) short short4v;
typedef __attribute__((ext_vector_type(4))) float floatx4;

__device__ __forceinline__ short f2b(float f) {
    __hip_bfloat16 h = __float2bfloat16(f);
    return *(short*)&h;
}
__device__ __forceinline__ float ldf(const float* p) { return *p; }
__device__ __forceinline__ float ldf(const __hip_bfloat16* p) { return __bfloat162float(*p); }

// ---------------------------------------------------------------------------
// Rank / permutation kernels (proven).
// ---------------------------------------------------------------------------

__global__ __launch_bounds__(256) void rank1_kernel(
    const int* __restrict__ idx, int* __restrict__ lrank,
    int* __restrict__ blockhist)
{
    __shared__ int sg[256];
    __shared__ int hist[NG];
    int t = threadIdx.x;
    int b = blockIdx.x;
    int j = b * 256 + t;
    for (int g = t; g < NG; g += 256) hist[g] = 0;
    int g = (j < NN) ? idx[j] : -1;
    sg[t] = g;
    __syncthreads();
    if (g >= 0) atomicAdd(&hist[g], 1);
    int r = 0;
    for (int s = 0; s < t; ++s) {
        if (sg[s] == g) r++;
    }
    __syncthreads();
    if (j < NN) lrank[j] = r;
    for (int gg = t; gg < NG; gg += 256) blockhist[gg * NB_PAD + b] = hist[gg];
}

__global__ __launch_bounds__(512) void rank2_kernel(
    const int* __restrict__ blockhist, int* __restrict__ blockoff,
    int* __restrict__ gs)
{
    __shared__ int tot[512];
    int g = threadIdx.x;
    int run = 0;
    if (g < NG) {
        int4 buf[NB_PAD / 4];
        const int4* src = (const int4*)(blockhist + g * NB_PAD);
#pragma unroll
        for (int i = 0; i < NB_PAD / 4; ++i) buf[i] = src[i];
        const int* bi = (const int*)buf;
#pragma unroll
        for (int b = 0; b < NB_RANK; ++b) {
            blockoff[g * NB_PAD + b] = run;
            run += bi[b];
        }
    }
    tot[threadIdx.x] = (g < NG) ? run : 0;
    __syncthreads();
#pragma unroll
    for (int off = 1; off < 512; off <<= 1) {
        int v = (threadIdx.x >= off) ? tot[threadIdx.x - off] : 0;
        __syncthreads();
        tot[threadIdx.x] += v;
        __syncthreads();
    }
    if (threadIdx.x == 0) gs[0] = 0;
    if (threadIdx.x < NG) gs[threadIdx.x + 1] = tot[threadIdx.x];
}

__global__ __launch_bounds__(256) void rank3_kernel(
    const int* __restrict__ idx, const int* __restrict__ lrank,
    const int* __restrict__ blockoff, const int* __restrict__ gs,
    float* __restrict__ dis, int* __restrict__ perm)
{
    int j = blockIdx.x * 256 + threadIdx.x;
    if (j >= NN) return;
    int g = idx[j];
    int r = blockoff[g * NB_PAD + blockIdx.x] + lrank[j];
    dis[j] = rsqrtf((float)(r + 1));
    perm[gs[g] + r] = j;
}

// ---------------------------------------------------------------------------
// Weight transposes fp32 [K][N] -> bf16 [N][K], one launch.
// ---------------------------------------------------------------------------

__global__ __launch_bounds__(256) void wt_all(
    const float* __restrict__ W1, const float* __restrict__ W2,
    const float* __restrict__ W3, __hip_bfloat16* __restrict__ Wt1,
    __hip_bfloat16* __restrict__ Wt2, __hip_bfloat16* __restrict__ Wt3)
{
    int o = blockIdx.x * 256 + threadIdx.x;
    if (o < D_IN * H1) {
        int n = o / D_IN, k = o - n * D_IN;
        Wt1[o] = __float2bfloat16(W1[(size_t)k * H1 + n]);
    } else if (o < D_IN * H1 + H1 * H2) {
        int p = o - D_IN * H1;
        int n = p / H1, k = p - n * H1;
        Wt2[p] = __float2bfloat16(W2[(size_t)k * H2 + n]);
    } else if (o < WT_ELEMS) {
        int p = o - D_IN * H1 - H1 * H2;
        int n = p / H2, k = p - n * H2;
        Wt3[p] = __float2bfloat16(W3[(size_t)k * D_OUT + n]);
    }
}

// ---------------------------------------------------------------------------
// Standalone segmented-prefix scan (MFMA triangular trick, verified R7/R9).
// Grid (NG, C/128), 256 threads (4 waves). Per 64-row chunk:
//   [sync] sp/sd [sync] stage T[c][r]=in[sp[r]][c]*sd[r] (bf16)
//   [sync] MFMA scan -> out[j][c] = sd[j]*(carry + cumsum), carries in regs
//   [sync] LNEP=0: copy O -> global bf16 (rows j<mt)
//          LNEP=1: F[j][c]=relu(val+b3[c]) fp32; LayerNorm rows -> out fp32
// Padded rows (j>=mt) have sd=0 -> contribute nothing; global writes guarded.
// ---------------------------------------------------------------------------

#define SCT 72    // T stride, [c][r] bf16
#define SCO 136   // O stride, [j][c] bf16
#define SF  132   // F stride, [j][c] fp32

template <typename TIN, int LNEP>
__global__ __launch_bounds__(256) void scan_kernel(
    const TIN* __restrict__ in, void* __restrict__ outv, int C,
    const float* __restrict__ b3, const float* __restrict__ gamma,
    const float* __restrict__ beta,
    const float* __restrict__ dis, const int* __restrict__ perm,
    const int* __restrict__ gs)
{
    __shared__ __align__(16) short T[128 * SCT];
    __shared__ __align__(16) char OB[LNEP ? (64 * SF * 4) : (64 * SCO * 2)];
    __shared__ __align__(16) float sd[64];
    __shared__ __align__(16) float b3s[128];
    __shared__ int sp[64];

    short* O = (short*)OB;
    float* F = (float*)OB;

    int tid = threadIdx.x;
    int w = tid >> 6;
    int lane = tid & 63;
    int quad = lane >> 4;
    int l15 = lane & 15;

    int g = blockIdx.x;
    int c0 = blockIdx.y * 128;
    int s = gs[g], cnt = gs[g + 1] - s;
    if (cnt <= 0) return;

    float2 gmv = make_float2(0.f, 0.f), btv = gmv;
    if (LNEP) {
        if (tid < 128) b3s[tid] = b3[tid];
        gmv = *(const float2*)&gamma[lane * 2];
        btv = *(const float2*)&beta[lane * 2];
    }

    // lower-triangular-ones B-frag generator (verified R7/R9)
    auto ltfrag = [&](int nt, int k2) -> short8 {
        int thr = nt * 16 + l15 - k2 * 32 - quad * 8;
        short8 f;
#pragma unroll
        for (int e = 0; e < 8; ++e)
            f[e] = (e <= thr) ? (short)0x3F80 : (short)0;
        return f;
    };

    float cr[2][4];
#pragma unroll
    for (int i = 0; i < 2; ++i)
#pragma unroll
        for (int r = 0; r < 4; ++r) cr[i][r] = 0.f;

    for (int base = 0; base < cnt; base += 64) {
        int mt = min(64, cnt - base);
        __syncthreads();
        if (tid < 64) {
            int p = (tid < mt) ? perm[s + base + tid] : perm[s];
            sp[tid] = p;
            sd[tid] = (tid < mt) ? dis[p] : 0.0f;
        }
        __syncthreads();

        float djn[4];
#pragma unroll
        for (int nt = 0; nt < 4; ++nt) djn[nt] = sd[nt * 16 + l15];

        // ---- stage: T[c][r] = bf16(in[sp[r]][c0+c] * sd[r]) ----
        {
            int c = tid & 127;
            int rh = (tid >> 7) * 8;
#pragma unroll
            for (int p = 0; p < 4; ++p) {
                int rb = rh + p * 16;
                short8 o;
#pragma unroll
                for (int e = 0; e < 8; ++e)
                    o[e] = f2b(ldf(in + (size_t)sp[rb + e] * C + c0 + c) * sd[rb + e]);
                *(short8*)&T[c * SCT + rb] = o;
            }
        }
        __syncthreads();

        // ---- MFMA scan: D[m=c][n=j]; wave w owns m-tiles 2w,2w+1 ----
        {
            floatx4 acc[2][4];
#pragma unroll
            for (int i = 0; i < 2; ++i)
#pragma unroll
                for (int nt = 0; nt < 4; ++nt) acc[i][nt] = (floatx4)0.0f;
#pragma unroll
            for (int k2 = 0; k2 < 2; ++k2) {
                short8 af[2];
#pragma unroll
                for (int i = 0; i < 2; ++i)
                    af[i] = *(const short8*)&T[((2 * w + i) * 16 + l15) * SCT + k2 * 32 + quad * 8];
#pragma unroll
                for (int nt = 0; nt < 4; ++nt) {
                    short8 lt = ltfrag(nt, k2);
#pragma unroll
                    for (int i = 0; i < 2; ++i)
                        acc[i][nt] = __builtin_amdgcn_mfma_f32_16x16x32_bf16(
                            af[i], lt, acc[i][nt], 0, 0, 0);
                }
            }
#pragma unroll
            for (int i = 0; i < 2; ++i) {
                float nc[4] = {0.f, 0.f, 0.f, 0.f};
#pragma unroll
                for (int nt = 0; nt < 4; ++nt) {
                    float tmp[4];
#pragma unroll
                    for (int r = 0; r < 4; ++r) tmp[r] = acc[i][nt][r] + cr[i][r];
                    if (nt == 3) {
#pragma unroll
                        for (int r = 0; r < 4; ++r) nc[r] = tmp[r];
                    }
                    if (LNEP) {
                        float4 bb = *(const float4*)&b3s[(2 * w + i) * 16 + quad * 4];
                        float4 o;
                        o.x = fmaxf(tmp[0] * djn[nt] + bb.x, 0.0f);
                        o.y = fmaxf(tmp[1] * djn[nt] + bb.y, 0.0f);
                        o.z = fmaxf(tmp[2] * djn[nt] + bb.z, 0.0f);
                        o.w = fmaxf(tmp[3] * djn[nt] + bb.w, 0.0f);
                        *(float4*)&F[(nt * 16 + l15) * SF + (2 * w + i) * 16 + quad * 4] = o;
                    } else {
                        short4v o4;
#pragma unroll
                        for (int r = 0; r < 4; ++r) o4[r] = f2b(tmp[r] * djn[nt]);
                        *(short4v*)&O[(nt * 16 + l15) * SCO + (2 * w + i) * 16 + quad * 4] = o4;
                    }
                }
#pragma unroll
                for (int r = 0; r < 4; ++r)
                    cr[i][r] = __shfl(nc[r], (lane & 48) + 15);
            }
        }
        __syncthreads();

        if (LNEP) {
            // ---- LayerNorm rows -> out (fp32, C==128) ----
            float* outp = (float*)outv;
            for (int r = w; r < mt; r += 4) {
                float2 v = *(const float2*)&F[r * SF + lane * 2];
                float s1 = v.x + v.y;
                float s2v = v.x * v.x + v.y * v.y;
#pragma unroll
                for (int off = 32; off > 0; off >>= 1) {
                    s1 += __shfl_down(s1, off);
                    s2v += __shfl_down(s2v, off);
                }
                s1 = __shfl(s1, 0);
                s2v = __shfl(s2v, 0);
                float mu = s1 * (1.0f / D_OUT);
                float var = s2v * (1.0f / D_OUT) - mu * mu;
                float rstd = rsqrtf(var + 1e-5f);
                float2 o;
                o.x = (v.x - mu) * rstd * gmv.x + btv.x;
                o.y = (v.y - mu) * rstd * gmv.y + btv.y;
                *(float2*)&outp[(size_t)sp[r] * D_OUT + lane * 2] = o;
            }
        } else {
            // ---- copy O -> global bf16, coalesced over c, guard j<mt ----
            short* outp = (short*)outv;
            int c = tid & 127;
            int jh = (tid >> 7) * 32;
            for (int k = 0; k < 32; ++k) {
                int j = jh + k;
                if (j < mt)
                    outp[(size_t)sp[j] * C + c0 + c] = O[j * SCO + c];
            }
        }
    }
}

// ---------------------------------------------------------------------------
// bf16 MFMA GEMM (R2-proven): C[M,N] = A[M,K] @ Bt[N,K]^T (+bias,relu if fuse)
// 128x128 tile, BK=64, 256 threads = 4 waves 2x2, 4x4 16x16x32 tiles/wave.
// ---------------------------------------------------------------------------

#define GBM 128
#define GBN 128
#define GBK 64
#define LDK 72

__global__ __launch_bounds__(256) void gemm_mfma(
    const __hip_bfloat16* __restrict__ A, const __hip_bfloat16* __restrict__ Bt,
    const float* __restrict__ bias, __hip_bfloat16* __restrict__ C,
    int M, int N, int K, int fuse)
{
    __shared__ short As[GBM * LDK];
    __shared__ short Bs[GBN * LDK];

    int tid = threadIdx.x;
    int wave = tid >> 6;
    int lane = tid & 63;
    int quad = lane >> 4;
    int l15 = lane & 15;
    int m0 = blockIdx.x * GBM;
    int n0 = blockIdx.y * GBN;
    int mw = (wave & 1) * 64;
    int nw = (wave >> 1) * 64;

    int sr = tid >> 3;
    int sc = (tid & 7) * 8;

    floatx4 acc[4][4];
#pragma unroll
    for (int i = 0; i < 4; ++i)
#pragma unroll
        for (int j = 0; j < 4; ++j) acc[i][j] = (floatx4)0.0f;

    const short8 zero8 = {0, 0, 0, 0, 0, 0, 0, 0};

    for (int kt = 0; kt < K; kt += GBK) {
        short8 av[4], bv[4];
#pragma unroll
        for (int r = 0; r < 4; ++r) {
            int row = sr + r * 32;
            int gm = m0 + row;
            av[r] = (gm < M)
                ? *(const short8*)((const short*)A + (size_t)gm * K + kt + sc)
                : zero8;
            int gn = n0 + row;
            bv[r] = *(const short8*)((const short*)Bt + (size_t)gn * K + kt + sc);
        }
        __syncthreads();
#pragma unroll
        for (int r = 0; r < 4; ++r) {
            *(short8*)&As[(sr + r * 32) * LDK + sc] = av[r];
            *(short8*)&Bs[(sr + r * 32) * LDK + sc] = bv[r];
        }
        __syncthreads();
#pragma unroll
        for (int kk = 0; kk < GBK; kk += 32) {
            short8 af[4], bf[4];
#pragma unroll
            for (int i = 0; i < 4; ++i)
                af[i] = *(const short8*)&As[(mw + i * 16 + l15) * LDK + kk + quad * 8];
#pragma unroll
            for (int j = 0; j < 4; ++j)
                bf[j] = *(const short8*)&Bs[(nw + j * 16 + l15) * LDK + kk + quad * 8];
#pragma unroll
            for (int i = 0; i < 4; ++i)
#pragma unroll
                for (int j = 0; j < 4; ++j)
                    acc[i][j] = __builtin_amdgcn_mfma_f32_16x16x32_bf16(
                        af[i], bf[j], acc[i][j], 0, 0, 0);
        }
    }

    float bj[4];
#pragma unroll
    for (int j = 0; j < 4; ++j)
        bj[j] = fuse ? bias[n0 + nw + j * 16 + l15] : 0.0f;
#pragma unroll
    for (int i = 0; i < 4; ++i) {
#pragma unroll
        for (int r = 0; r < 4; ++r) {
            int grow = m0 + mw + i * 16 + quad * 4 + r;
            if (grow < M) {
#pragma unroll
                for (int j = 0; j < 4; ++j) {
                    float v = acc[i][j][r];
                    if (fuse) v = fmaxf(v + bj[j], 0.0f);
                    C[(size_t)grow * N + n0 + nw + j * 16 + l15] = __float2bfloat16(v);
                }
            }
        }
    }
}

// ---------------------------------------------------------------------------

extern "C" void kernel_launch(void* const* d_in, const int* in_sizes, int n_in,
                              void* d_out, int out_size, void* d_ws, size_t ws_size,
                              hipStream_t stream) {
    const float* x     = (const float*)d_in[0];
    const int*   idx   = (const int*)d_in[1];
    const float* W1    = (const float*)d_in[2];
    const float* b1    = (const float*)d_in[3];
    const float* W2    = (const float*)d_in[4];
    const float* b2    = (const float*)d_in[5];
    const float* W3    = (const float*)d_in[6];
    const float* b3    = (const float*)d_in[7];
    const float* gamma = (const float*)d_in[8];
    const float* beta  = (const float*)d_in[9];
    float* out = (float*)d_out;

    char* ws = (char*)d_ws;
    size_t off = 0;
    auto alloc = [&](size_t bytes) -> void* {
        void* p = (void*)(ws + off);
        off += (bytes + 255) & ~(size_t)255;
        return p;
    };
    float* dis   = (float*)alloc(NN * sizeof(float));
    int*   perm  = (int*)alloc(NN * sizeof(int));
    int*   lrank = (int*)alloc(NN * sizeof(int));
    int*   gs    = (int*)alloc((NG + 1) * sizeof(int));
    int*   bhist = (int*)alloc(NG * NB_PAD * sizeof(int));
    int*   boff  = (int*)alloc(NG * NB_PAD * sizeof(int));
    __hip_bfloat16* Wt1 = (__hip_bfloat16*)alloc((size_t)D_IN * H1 * 2);
    __hip_bfloat16* Wt2 = (__hip_bfloat16*)alloc((size_t)H1 * H2 * 2);
    __hip_bfloat16* Wt3 = (__hip_bfloat16*)alloc((size_t)H2 * D_OUT * 2);
    __hip_bfloat16* A1  = (__hip_bfloat16*)alloc((size_t)NN * D_IN * 2);
    __hip_bfloat16* h1  = (__hip_bfloat16*)alloc((size_t)NN * H1 * 2);
    __hip_bfloat16* A2  = (__hip_bfloat16*)alloc((size_t)NN * H1 * 2);
    __hip_bfloat16* h2  = (__hip_bfloat16*)alloc((size_t)NN * H2 * 2);
    __hip_bfloat16* P   = (__hip_bfloat16*)alloc((size_t)NN * D_OUT * 2);

    // graph structure + weights
    rank1_kernel<<<NB_RANK, 256, 0, stream>>>(idx, lrank, bhist);
    rank2_kernel<<<1, 512, 0, stream>>>(bhist, boff, gs);
    rank3_kernel<<<NB_RANK, 256, 0, stream>>>(idx, lrank, boff, gs, dis, perm);
    wt_all<<<(WT_ELEMS + 255) / 256, 256, 0, stream>>>(
        W1, W2, W3, Wt1, Wt2, Wt3);

    int gm = (NN + GBM - 1) / GBM;   // 157

    // layer 1: A1 = Agg(x); h1 = relu(A1 @ W1 + b1)
    scan_kernel<float, 0><<<dim3(NG, 1), 256, 0, stream>>>(
        x, A1, D_IN, nullptr, nullptr, nullptr, dis, perm, gs);
    gemm_mfma<<<dim3(gm, H1 / GBN), 256, 0, stream>>>(
        A1, Wt1, b1, h1, NN, H1, D_IN, 1);

    // layer 2: A2 = Agg(h1); h2 = relu(A2 @ W2 + b2)
    scan_kernel<__hip_bfloat16, 0><<<dim3(NG, H1 / 128), 256, 0, stream>>>(
        h1, A2, H1, nullptr, nullptr, nullptr, dis, perm, gs);
    gemm_mfma<<<dim3(gm, H2 / GBN), 256, 0, stream>>>(
        A2, Wt2, b2, h2, NN, H2, H1, 1);

    // layer 3: P = h2 @ W3; out = LN(relu(Agg(P) + b3))
    gemm_mfma<<<dim3(gm, D_OUT / GBN), 256, 0, stream>>>(
        h2, Wt3, nullptr, P, NN, D_OUT, H2, 0);
    scan_kernel<__hip_bfloat16, 1><<<dim3(NG, 1), 256, 0, stream>>>(
        P, out, D_OUT, b3, gamma, beta, dis, perm, gs);
}

// Round 13
// 152.787 us; speedup vs baseline: 1.1714x; 1.1714x over previous
//
#include <hip/hip_runtime.h>
#include <hip/hip_bf16.h>

// Problem constants (GCN_66649302499531)
#define NN 20000
#define NG 400
#define D_IN 128
#define H1 256
#define H2 256
#define D_OUT 128
#define NB_RANK ((NN + 255) / 256)   // 79
#define NB_PAD 80
#define WT_ELEMS (D_IN * H1 + H1 * H2 + H2 * D_OUT)   // 131072

typedef __attribute__((ext_vector_type(8))) short short8;
typedef __attribute__((ext_vector_type(4))) short short4v;
typedef __attribute__((ext_vector_type(4))) float floatx4;

__device__ __forceinline__ short f2b(float f) {
    __hip_bfloat16 h = __float2bfloat16(f);
    return *(short*)&h;
}

// async global->LDS DMA, 16B/lane: per-lane global addr, wave-uniform LDS base.
// Only used from fully-unrolled loops (rolled-loop usage miscompiled in R11).
__device__ __forceinline__ void gl_lds16(const void* g, void* l) {
    __builtin_amdgcn_global_load_lds(
        (__attribute__((address_space(1))) void*)g,
        (__attribute__((address_space(3))) void*)l, 16, 0, 0);
}

// ---------------------------------------------------------------------------
// Rank / permutation kernels (proven).
// ---------------------------------------------------------------------------

__global__ __launch_bounds__(256) void rank1_kernel(
    const int* __restrict__ idx, int* __restrict__ lrank,
    int* __restrict__ blockhist)
{
    __shared__ int sg[256];
    __shared__ int hist[NG];
    int t = threadIdx.x;
    int b = blockIdx.x;
    int j = b * 256 + t;
    for (int g = t; g < NG; g += 256) hist[g] = 0;
    int g = (j < NN) ? idx[j] : -1;
    sg[t] = g;
    __syncthreads();
    if (g >= 0) atomicAdd(&hist[g], 1);
    int r = 0;
    for (int s = 0; s < t; ++s) {
        if (sg[s] == g) r++;
    }
    __syncthreads();
    if (j < NN) lrank[j] = r;
    for (int gg = t; gg < NG; gg += 256) blockhist[gg * NB_PAD + b] = hist[gg];
}

__global__ __launch_bounds__(512) void rank2_kernel(
    const int* __restrict__ blockhist, int* __restrict__ blockoff,
    int* __restrict__ gs)
{
    __shared__ int tot[512];
    int g = threadIdx.x;
    int run = 0;
    if (g < NG) {
        int4 buf[NB_PAD / 4];
        const int4* src = (const int4*)(blockhist + g * NB_PAD);
#pragma unroll
        for (int i = 0; i < NB_PAD / 4; ++i) buf[i] = src[i];
        const int* bi = (const int*)buf;
#pragma unroll
        for (int b = 0; b < NB_RANK; ++b) {
            blockoff[g * NB_PAD + b] = run;
            run += bi[b];
        }
    }
    tot[threadIdx.x] = (g < NG) ? run : 0;
    __syncthreads();
#pragma unroll
    for (int off = 1; off < 512; off <<= 1) {
        int v = (threadIdx.x >= off) ? tot[threadIdx.x - off] : 0;
        __syncthreads();
        tot[threadIdx.x] += v;
        __syncthreads();
    }
    if (threadIdx.x == 0) gs[0] = 0;
    if (threadIdx.x < NG) gs[threadIdx.x + 1] = tot[threadIdx.x];
}

__global__ __launch_bounds__(256) void rank3_kernel(
    const int* __restrict__ idx, const int* __restrict__ lrank,
    const int* __restrict__ blockoff, const int* __restrict__ gs,
    float* __restrict__ dis, int* __restrict__ perm)
{
    int j = blockIdx.x * 256 + threadIdx.x;
    if (j >= NN) return;
    int g = idx[j];
    int r = blockoff[g * NB_PAD + blockIdx.x] + lrank[j];
    dis[j] = rsqrtf((float)(r + 1));
    perm[gs[g] + r] = j;
}

// ---------------------------------------------------------------------------
// Weight transposes fp32 [K][N] -> bf16 [N][K], one launch.
// ---------------------------------------------------------------------------

__global__ __launch_bounds__(256) void wt_all(
    const float* __restrict__ W1, const float* __restrict__ W2,
    const float* __restrict__ W3, __hip_bfloat16* __restrict__ Wt1,
    __hip_bfloat16* __restrict__ Wt2, __hip_bfloat16* __restrict__ Wt3)
{
    int o = blockIdx.x * 256 + threadIdx.x;
    if (o < D_IN * H1) {
        int n = o / D_IN, k = o - n * D_IN;
        Wt1[o] = __float2bfloat16(W1[(size_t)k * H1 + n]);
    } else if (o < D_IN * H1 + H1 * H2) {
        int p = o - D_IN * H1;
        int n = p / H1, k = p - n * H1;
        Wt2[p] = __float2bfloat16(W2[(size_t)k * H2 + n]);
    } else if (o < WT_ELEMS) {
        int p = o - D_IN * H1 - H1 * H2;
        int n = p / H2, k = p - n * H2;
        Wt3[p] = __float2bfloat16(W3[(size_t)k * D_OUT + n]);
    }
}

// ---------------------------------------------------------------------------
// Fused per-group pipeline — R9 math, 8 WAVES (512 threads) per block.
// Per-wave tile multiplicity halved vs R9 -> ~half the unrolled code
// (fits I$), ~half the per-stage critical path (8 waves per barrier-stage),
// ~half the register pressure (no 256-VGPR pin / scratch spill).
// No '#pragma unroll 1' anywhere (R11/R12: that pragma corrupted numerics).
// ---------------------------------------------------------------------------

#define ST1 72
#define SA1 136
#define ST2 72
#define SA2 264
#define SH2 264
#define ST3 72
#define SF 132

__global__ __launch_bounds__(512) void fused_gcn(
    const float* __restrict__ x,
    const __hip_bfloat16* __restrict__ Wt1_,
    const __hip_bfloat16* __restrict__ Wt2_,
    const __hip_bfloat16* __restrict__ Wt3_,
    const float* __restrict__ b1, const float* __restrict__ b2,
    const float* __restrict__ b3,
    const float* __restrict__ gamma, const float* __restrict__ beta,
    const float* __restrict__ dis, const int* __restrict__ perm,
    const int* __restrict__ gs,
    float* __restrict__ out)
{
    __shared__ __align__(16) char RA[36864];   // XR | T2 | HB | F
    __shared__ __align__(16) char RB[36864];   // T1+A1 | A2 | T3
    __shared__ __align__(16) float b2s[256];
    __shared__ __align__(16) float b3s[128];
    __shared__ __align__(16) float sd[64];
    __shared__ int sp[64];

    float* XR = (float*)RA;                    // 64 x 128 fp32
    short* T2 = (short*)RA;                    // 256 x 72 bf16 (c-major h1)
    short* HB = (short*)RA;                    // 64 x 264 bf16 (h2)
    float* F  = (float*)RA;                    // 64 x 132 fp32
    short* T1 = (short*)RB;                    // 128 x 72 bf16
    short* A1 = (short*)(RB + 18432);          // 64 x 136 bf16
    short* A2 = (short*)RB;                    // 64 x 264 bf16
    short* T3 = (short*)RB;                    // 128 x 72 bf16

    const short* Wt1 = (const short*)Wt1_;
    const short* Wt2 = (const short*)Wt2_;
    const short* Wt3 = (const short*)Wt3_;

    int tid = threadIdx.x;
    int w = tid >> 6;          // wave 0..7
    int lane = tid & 63;
    int quad = lane >> 4;
    int l15 = lane & 15;

    int g = blockIdx.x;
    int s = gs[g], cnt = gs[g + 1] - s;
    if (cnt <= 0) return;

    if (tid < 256) b2s[tid] = b2[tid];
    if (tid < 128) b3s[tid] = b3[tid];

    float bj1[2];              // GEMM1 bias: wave owns n-tiles 2w..2w+1
#pragma unroll
    for (int nt = 0; nt < 2; ++nt) bj1[nt] = b1[(w * 2 + nt) * 16 + l15];
    float2 gmv = *(const float2*)&gamma[lane * 2];
    float2 btv = *(const float2*)&beta[lane * 2];

    // lower-triangular-ones B-frag generator (verified R7/R9/R10)
    auto ltfrag = [&](int nt, int k2) -> short8 {
        int thr = nt * 16 + l15 - k2 * 32 - quad * 8;
        short8 f;
#pragma unroll
        for (int e = 0; e < 8; ++e)
            f[e] = (e <= thr) ? (short)0x3F80 : (short)0;
        return f;
    };

    float c1[4], c2[2][4], c3[4];
#pragma unroll
    for (int r = 0; r < 4; ++r) {
        c1[r] = 0.f; c3[r] = 0.f;
        c2[0][r] = 0.f; c2[1][r] = 0.f;
    }

    for (int base = 0; base < cnt; base += 64) {
        int mt = min(64, cnt - base);
        __syncthreads();   // prev chunk LN done with F/sp
        if (tid < 64) {
            int p = (tid < mt) ? perm[s + base + tid] : perm[s];
            sp[tid] = p;
            sd[tid] = (tid < mt) ? dis[p] : 0.0f;
        }
        __syncthreads();

        float djn[4];
#pragma unroll
        for (int nt = 0; nt < 4; ++nt) djn[nt] = sd[nt * 16 + l15];

        // ---- stage x: DMA 64 rows of x -> XR; wave w owns rows 8w..8w+7 ----
        {
            int r0 = 8 * w;
#pragma unroll
            for (int ii = 0; ii < 4; ++ii) {
                int row = r0 + 2 * ii + (lane >> 5);
                const float* src = x + (size_t)sp[row] * D_IN + (lane & 31) * 4;
                gl_lds16(src, &XR[(r0 + 2 * ii) * D_IN]);
            }
        }
        __syncthreads();

        // ---- repack: T1[c][r] = bf16(XR[r][c] * sd[r]); 512 thr, 16 rows ea ----
        {
            int c = tid & 127;
            int q = tid >> 7;   // 0..3
#pragma unroll
            for (int p = 0; p < 2; ++p) {
                int rb = q * 16 + p * 8;
                short8 o;
#pragma unroll
                for (int e = 0; e < 8; ++e)
                    o[e] = f2b(XR[(rb + e) * D_IN + c] * sd[rb + e]);
                *(short8*)&T1[c * ST1 + rb] = o;
            }
        }
        __syncthreads();

        // ---- scan1 (MFMA): A1[j][c] = dj*(c1 + cumsum(T1)); 1 m-tile/wave ----
        {
            floatx4 acc[4];
#pragma unroll
            for (int nt = 0; nt < 4; ++nt) acc[nt] = (floatx4)0.0f;
#pragma unroll
            for (int k2 = 0; k2 < 2; ++k2) {
                short8 af = *(const short8*)&T1[(w * 16 + l15) * ST1 + k2 * 32 + quad * 8];
#pragma unroll
                for (int nt = 0; nt < 4; ++nt)
                    acc[nt] = __builtin_amdgcn_mfma_f32_16x16x32_bf16(
                        af, ltfrag(nt, k2), acc[nt], 0, 0, 0);
            }
            float nc[4] = {0.f, 0.f, 0.f, 0.f};
#pragma unroll
            for (int nt = 0; nt < 4; ++nt) {
                float tmp[4];
#pragma unroll
                for (int r = 0; r < 4; ++r) tmp[r] = acc[nt][r] + c1[r];
                if (nt == 3) {
#pragma unroll
                    for (int r = 0; r < 4; ++r) nc[r] = tmp[r];
                }
                short4v o4;
#pragma unroll
                for (int r = 0; r < 4; ++r) o4[r] = f2b(tmp[r] * djn[nt]);
                *(short4v*)&A1[(nt * 16 + l15) * SA1 + w * 16 + quad * 4] = o4;
            }
#pragma unroll
            for (int r = 0; r < 4; ++r)
                c1[r] = __shfl(nc[r], (lane & 48) + 15);
        }
        __syncthreads();

        // ---- GEMM1: T2[c][j] = relu(A1 @ Wt1^T + b1)*sd[j]; 2 n-tiles/wave ----
        {
            floatx4 acc[4][2];
#pragma unroll
            for (int i = 0; i < 4; ++i)
#pragma unroll
                for (int nt = 0; nt < 2; ++nt) acc[i][nt] = (floatx4)0.0f;
#pragma unroll
            for (int kk = 0; kk < 4; ++kk) {   // K = 128
                short8 af[4], bf[2];
#pragma unroll
                for (int i = 0; i < 4; ++i)
                    af[i] = *(const short8*)&A1[(i * 16 + l15) * SA1 + kk * 32 + quad * 8];
#pragma unroll
                for (int nt = 0; nt < 2; ++nt)
                    bf[nt] = *(const short8*)&Wt1[((size_t)(w * 2 + nt) * 16 + l15) * D_IN + kk * 32 + quad * 8];
#pragma unroll
                for (int i = 0; i < 4; ++i)
#pragma unroll
                    for (int nt = 0; nt < 2; ++nt)
                        acc[i][nt] = __builtin_amdgcn_mfma_f32_16x16x32_bf16(
                            af[i], bf[nt], acc[i][nt], 0, 0, 0);
            }
#pragma unroll
            for (int i = 0; i < 4; ++i) {
                float4 sdv = *(const float4*)&sd[i * 16 + quad * 4];   // sd[j]
#pragma unroll
                for (int nt = 0; nt < 2; ++nt) {
                    short4v o4;
                    o4[0] = f2b(fmaxf(acc[i][nt][0] + bj1[nt], 0.0f) * sdv.x);
                    o4[1] = f2b(fmaxf(acc[i][nt][1] + bj1[nt], 0.0f) * sdv.y);
                    o4[2] = f2b(fmaxf(acc[i][nt][2] + bj1[nt], 0.0f) * sdv.z);
                    o4[3] = f2b(fmaxf(acc[i][nt][3] + bj1[nt], 0.0f) * sdv.w);
                    *(short4v*)&T2[((w * 2 + nt) * 16 + l15) * ST2 + i * 16 + quad * 4] = o4;
                }
            }
        }
        __syncthreads();

        // ---- scan2 (MFMA): A2[j][c] = dj*(c2 + cumsum(T2)); 2 m-tiles/wave ----
        {
            floatx4 acc[2][4];
#pragma unroll
            for (int i = 0; i < 2; ++i)
#pragma unroll
                for (int nt = 0; nt < 4; ++nt) acc[i][nt] = (floatx4)0.0f;
#pragma unroll
            for (int k2 = 0; k2 < 2; ++k2) {
                short8 af[2];
#pragma unroll
                for (int i = 0; i < 2; ++i)
                    af[i] = *(const short8*)&T2[((2 * w + i) * 16 + l15) * ST2 + k2 * 32 + quad * 8];
#pragma unroll
                for (int nt = 0; nt < 4; ++nt) {
                    short8 lt = ltfrag(nt, k2);
#pragma unroll
                    for (int i = 0; i < 2; ++i)
                        acc[i][nt] = __builtin_amdgcn_mfma_f32_16x16x32_bf16(
                            af[i], lt, acc[i][nt], 0, 0, 0);
                }
            }
#pragma unroll
            for (int i = 0; i < 2; ++i) {
                float nc[4] = {0.f, 0.f, 0.f, 0.f};
#pragma unroll
                for (int nt = 0; nt < 4; ++nt) {
                    float tmp[4];
#pragma unroll
                    for (int r = 0; r < 4; ++r) tmp[r] = acc[i][nt][r] + c2[i][r];
                    if (nt == 3) {
#pragma unroll
                        for (int r = 0; r < 4; ++r) nc[r] = tmp[r];
                    }
                    short4v o4;
#pragma unroll
                    for (int r = 0; r < 4; ++r) o4[r] = f2b(tmp[r] * djn[nt]);
                    *(short4v*)&A2[(nt * 16 + l15) * SA2 + (2 * w + i) * 16 + quad * 4] = o4;
                }
#pragma unroll
                for (int r = 0; r < 4; ++r)
                    c2[i][r] = __shfl(nc[r], (lane & 48) + 15);
            }
        }
        __syncthreads();

        // ---- GEMM2: HB[j][c2] = relu(A2 @ Wt2^T + b2); 2 m-tiles/wave ----
        {
            floatx4 acc[2][4];
#pragma unroll
            for (int i = 0; i < 2; ++i)
#pragma unroll
                for (int nt = 0; nt < 4; ++nt) acc[i][nt] = (floatx4)0.0f;
#pragma unroll
            for (int kk = 0; kk < 8; ++kk) {   // K = 256
                short8 af[2], bf[4];
#pragma unroll
                for (int i = 0; i < 2; ++i)
                    af[i] = *(const short8*)&Wt2[((size_t)(2 * w + i) * 16 + l15) * H1 + kk * 32 + quad * 8];
#pragma unroll
                for (int nt = 0; nt < 4; ++nt)
                    bf[nt] = *(const short8*)&A2[(nt * 16 + l15) * SA2 + kk * 32 + quad * 8];
#pragma unroll
                for (int i = 0; i < 2; ++i)
#pragma unroll
                    for (int nt = 0; nt < 4; ++nt)
                        acc[i][nt] = __builtin_amdgcn_mfma_f32_16x16x32_bf16(
                            af[i], bf[nt], acc[i][nt], 0, 0, 0);
            }
#pragma unroll
            for (int i = 0; i < 2; ++i) {
                float4 bb = *(const float4*)&b2s[(2 * w + i) * 16 + quad * 4];
#pragma unroll
                for (int nt = 0; nt < 4; ++nt) {
                    short4v o4;
                    o4[0] = f2b(fmaxf(acc[i][nt][0] + bb.x, 0.0f));
                    o4[1] = f2b(fmaxf(acc[i][nt][1] + bb.y, 0.0f));
                    o4[2] = f2b(fmaxf(acc[i][nt][2] + bb.z, 0.0f));
                    o4[3] = f2b(fmaxf(acc[i][nt][3] + bb.w, 0.0f));
                    *(short4v*)&HB[(nt * 16 + l15) * SH2 + (2 * w + i) * 16 + quad * 4] = o4;
                }
            }
        }
        __syncthreads();

        // ---- GEMM3: T3[d][j] = (HB @ Wt3^T)[j][d]*sd[j]; 1 n-tile/wave ----
        {
            floatx4 acc[4];
#pragma unroll
            for (int i = 0; i < 4; ++i) acc[i] = (floatx4)0.0f;
#pragma unroll
            for (int kk = 0; kk < 8; ++kk) {   // K = 256
                short8 bf = *(const short8*)&Wt3[((size_t)w * 16 + l15) * H2 + kk * 32 + quad * 8];
#pragma unroll
                for (int i = 0; i < 4; ++i) {
                    short8 af = *(const short8*)&HB[(i * 16 + l15) * SH2 + kk * 32 + quad * 8];
                    acc[i] = __builtin_amdgcn_mfma_f32_16x16x32_bf16(
                        af, bf, acc[i], 0, 0, 0);
                }
            }
#pragma unroll
            for (int i = 0; i < 4; ++i) {
                float4 sdv = *(const float4*)&sd[i * 16 + quad * 4];
                short4v o4;
                o4[0] = f2b(acc[i][0] * sdv.x);
                o4[1] = f2b(acc[i][1] * sdv.y);
                o4[2] = f2b(acc[i][2] * sdv.z);
                o4[3] = f2b(acc[i][3] * sdv.w);
                *(short4v*)&T3[(w * 16 + l15) * ST3 + i * 16 + quad * 4] = o4;
            }
        }
        __syncthreads();

        // ---- scan3 (MFMA): F[j][d] = relu(dj*(c3+cumsum(T3))+b3); 1 m-tile/wave
        {
            floatx4 acc[4];
#pragma unroll
            for (int nt = 0; nt < 4; ++nt) acc[nt] = (floatx4)0.0f;
#pragma unroll
            for (int k2 = 0; k2 < 2; ++k2) {
                short8 af = *(const short8*)&T3[(w * 16 + l15) * ST3 + k2 * 32 + quad * 8];
#pragma unroll
                for (int nt = 0; nt < 4; ++nt)
                    acc[nt] = __builtin_amdgcn_mfma_f32_16x16x32_bf16(
                        af, ltfrag(nt, k2), acc[nt], 0, 0, 0);
            }
            float4 bb = *(const float4*)&b3s[w * 16 + quad * 4];
            float nc[4] = {0.f, 0.f, 0.f, 0.f};
#pragma unroll
            for (int nt = 0; nt < 4; ++nt) {
                float tmp[4];
#pragma unroll
                for (int r = 0; r < 4; ++r) tmp[r] = acc[nt][r] + c3[r];
                if (nt == 3) {
#pragma unroll
                    for (int r = 0; r < 4; ++r) nc[r] = tmp[r];
                }
                float4 o;
                o.x = fmaxf(tmp[0] * djn[nt] + bb.x, 0.0f);
                o.y = fmaxf(tmp[1] * djn[nt] + bb.y, 0.0f);
                o.z = fmaxf(tmp[2] * djn[nt] + bb.z, 0.0f);
                o.w = fmaxf(tmp[3] * djn[nt] + bb.w, 0.0f);
                *(float4*)&F[(nt * 16 + l15) * SF + w * 16 + quad * 4] = o;
            }
#pragma unroll
            for (int r = 0; r < 4; ++r)
                c3[r] = __shfl(nc[r], (lane & 48) + 15);
        }
        __syncthreads();

        // ---- LayerNorm rows -> out (8 waves: rows w, w+8, ...) ----
        for (int r = w; r < mt; r += 8) {
            float2 v = *(const float2*)&F[r * SF + lane * 2];
            float s1 = v.x + v.y;
            float s2v = v.x * v.x + v.y * v.y;
#pragma unroll
            for (int off = 32; off > 0; off >>= 1) {
                s1 += __shfl_down(s1, off);
                s2v += __shfl_down(s2v, off);
            }
            s1 = __shfl(s1, 0);
            s2v = __shfl(s2v, 0);
            float mu = s1 * (1.0f / D_OUT);
            float var = s2v * (1.0f / D_OUT) - mu * mu;
            float rstd = rsqrtf(var + 1e-5f);
            float2 o;
            o.x = (v.x - mu) * rstd * gmv.x + btv.x;
            o.y = (v.y - mu) * rstd * gmv.y + btv.y;
            *(float2*)&out[(size_t)sp[r] * D_OUT + lane * 2] = o;
        }
    }
}

// ---------------------------------------------------------------------------

extern "C" void kernel_launch(void* const* d_in, const int* in_sizes, int n_in,
                              void* d_out, int out_size, void* d_ws, size_t ws_size,
                              hipStream_t stream) {
    const float* x     = (const float*)d_in[0];
    const int*   idx   = (const int*)d_in[1];
    const float* W1    = (const float*)d_in[2];
    const float* b1    = (const float*)d_in[3];
    const float* W2    = (const float*)d_in[4];
    const float* b2    = (const float*)d_in[5];
    const float* W3    = (const float*)d_in[6];
    const float* b3    = (const float*)d_in[7];
    const float* gamma = (const float*)d_in[8];
    const float* beta  = (const float*)d_in[9];
    float* out = (float*)d_out;

    char* ws = (char*)d_ws;
    size_t off = 0;
    auto alloc = [&](size_t bytes) -> void* {
        void* p = (void*)(ws + off);
        off += (bytes + 255) & ~(size_t)255;
        return p;
    };
    float* dis   = (float*)alloc(NN * sizeof(float));
    int*   perm  = (int*)alloc(NN * sizeof(int));
    int*   lrank = (int*)alloc(NN * sizeof(int));
    int*   gs    = (int*)alloc((NG + 1) * sizeof(int));
    int*   bhist = (int*)alloc(NG * NB_PAD * sizeof(int));
    int*   boff  = (int*)alloc(NG * NB_PAD * sizeof(int));
    __hip_bfloat16* Wt1 = (__hip_bfloat16*)alloc((size_t)D_IN * H1 * 2);
    __hip_bfloat16* Wt2 = (__hip_bfloat16*)alloc((size_t)H1 * H2 * 2);
    __hip_bfloat16* Wt3 = (__hip_bfloat16*)alloc((size_t)H2 * D_OUT * 2);

    rank1_kernel<<<NB_RANK, 256, 0, stream>>>(idx, lrank, bhist);
    rank2_kernel<<<1, 512, 0, stream>>>(bhist, boff, gs);
    rank3_kernel<<<NB_RANK, 256, 0, stream>>>(idx, lrank, boff, gs, dis, perm);
    wt_all<<<(WT_ELEMS + 255) / 256, 256, 0, stream>>>(
        W1, W2, W3, Wt1, Wt2, Wt3);

    fused_gcn<<<NG, 512, 0, stream>>>(
        x, Wt1, Wt2, Wt3, b1, b2, b3, gamma, beta, dis, perm, gs, out);
}

// Round 14
// 141.591 us; speedup vs baseline: 1.2640x; 1.0791x over previous
//
#include <hip/hip_runtime.h>
#include <hip/hip_bf16.h>

// Problem constants (GCN_66649302499531)
#define NN 20000
#define NG 400
#define D_IN 128
#define H1 256
#define H2 256
#define D_OUT 128
#define NB_RANK ((NN + 255) / 256)   // 79
#define NB_PAD 80
#define WT_ELEMS (D_IN * H1 + H1 * H2 + H2 * D_OUT)   // 131072

typedef __attribute__((ext_vector_type(8))) short short8;
typedef __attribute__((ext_vector_type(4))) short short4v;
typedef __attribute__((ext_vector_type(4))) float floatx4;

__device__ __forceinline__ short f2b(float f) {
    __hip_bfloat16 h = __float2bfloat16(f);
    return *(short*)&h;
}

// async global->LDS DMA, 16B/lane: per-lane global addr, wave-uniform LDS base.
// Only used from fully-unrolled loops (rolled-loop usage miscompiled in R11).
__device__ __forceinline__ void gl_lds16(const void* g, void* l) {
    __builtin_amdgcn_global_load_lds(
        (__attribute__((address_space(1))) void*)g,
        (__attribute__((address_space(3))) void*)l, 16, 0, 0);
}

// ---------------------------------------------------------------------------
// Rank / permutation kernels (proven).
// ---------------------------------------------------------------------------

__global__ __launch_bounds__(256) void rank1_kernel(
    const int* __restrict__ idx, int* __restrict__ lrank,
    int* __restrict__ blockhist)
{
    __shared__ int sg[256];
    __shared__ int hist[NG];
    int t = threadIdx.x;
    int b = blockIdx.x;
    int j = b * 256 + t;
    for (int g = t; g < NG; g += 256) hist[g] = 0;
    int g = (j < NN) ? idx[j] : -1;
    sg[t] = g;
    __syncthreads();
    if (g >= 0) atomicAdd(&hist[g], 1);
    int r = 0;
    for (int s = 0; s < t; ++s) {
        if (sg[s] == g) r++;
    }
    __syncthreads();
    if (j < NN) lrank[j] = r;
    for (int gg = t; gg < NG; gg += 256) blockhist[gg * NB_PAD + b] = hist[gg];
}

__global__ __launch_bounds__(512) void rank2_kernel(
    const int* __restrict__ blockhist, int* __restrict__ blockoff,
    int* __restrict__ gs)
{
    __shared__ int tot[512];
    int g = threadIdx.x;
    int run = 0;
    if (g < NG) {
        int4 buf[NB_PAD / 4];
        const int4* src = (const int4*)(blockhist + g * NB_PAD);
#pragma unroll
        for (int i = 0; i < NB_PAD / 4; ++i) buf[i] = src[i];
        const int* bi = (const int*)buf;
#pragma unroll
        for (int b = 0; b < NB_RANK; ++b) {
            blockoff[g * NB_PAD + b] = run;
            run += bi[b];
        }
    }
    tot[threadIdx.x] = (g < NG) ? run : 0;
    __syncthreads();
#pragma unroll
    for (int off = 1; off < 512; off <<= 1) {
        int v = (threadIdx.x >= off) ? tot[threadIdx.x - off] : 0;
        __syncthreads();
        tot[threadIdx.x] += v;
        __syncthreads();
    }
    if (threadIdx.x == 0) gs[0] = 0;
    if (threadIdx.x < NG) gs[threadIdx.x + 1] = tot[threadIdx.x];
}

__global__ __launch_bounds__(256) void rank3_kernel(
    const int* __restrict__ idx, const int* __restrict__ lrank,
    const int* __restrict__ blockoff, const int* __restrict__ gs,
    float* __restrict__ dis, int* __restrict__ perm)
{
    int j = blockIdx.x * 256 + threadIdx.x;
    if (j >= NN) return;
    int g = idx[j];
    int r = blockoff[g * NB_PAD + blockIdx.x] + lrank[j];
    dis[j] = rsqrtf((float)(r + 1));
    perm[gs[g] + r] = j;
}

// ---------------------------------------------------------------------------
// Weight transposes fp32 [K][N] -> bf16 [N][K], one launch.
// ---------------------------------------------------------------------------

__global__ __launch_bounds__(256) void wt_all(
    const float* __restrict__ W1, const float* __restrict__ W2,
    const float* __restrict__ W3, __hip_bfloat16* __restrict__ Wt1,
    __hip_bfloat16* __restrict__ Wt2, __hip_bfloat16* __restrict__ Wt3)
{
    int o = blockIdx.x * 256 + threadIdx.x;
    if (o < D_IN * H1) {
        int n = o / D_IN, k = o - n * D_IN;
        Wt1[o] = __float2bfloat16(W1[(size_t)k * H1 + n]);
    } else if (o < D_IN * H1 + H1 * H2) {
        int p = o - D_IN * H1;
        int n = p / H1, k = p - n * H1;
        Wt2[p] = __float2bfloat16(W2[(size_t)k * H2 + n]);
    } else if (o < WT_ELEMS) {
        int p = o - D_IN * H1 - H1 * H2;
        int n = p / H2, k = p - n * H2;
        Wt3[p] = __float2bfloat16(W3[(size_t)k * D_OUT + n]);
    }
}

// ---------------------------------------------------------------------------
// Fused per-group pipeline — R13 structure (8 waves / 512 threads) with ONE
// change: the weight pointers are re-defined each chunk iteration via empty
// inline asm, breaking LICM. R13 evidence: the compiler hoisted all 32 short8
// weight frags (=128 VGPRs) out of the chunk loop, hit the 128-VGPR occupancy
// cap, and spilled ~19 MB/dispatch to scratch (WRITE_SIZE 29.6 vs 10.2 MB
// output). Opaque pointers keep weight-load live ranges inside each stage.
// ---------------------------------------------------------------------------

#define ST1 72
#define SA1 136
#define ST2 72
#define SA2 264
#define SH2 264
#define ST3 72
#define SF 132

__global__ __launch_bounds__(512) void fused_gcn(
    const float* __restrict__ x,
    const __hip_bfloat16* __restrict__ Wt1_,
    const __hip_bfloat16* __restrict__ Wt2_,
    const __hip_bfloat16* __restrict__ Wt3_,
    const float* __restrict__ b1, const float* __restrict__ b2,
    const float* __restrict__ b3,
    const float* __restrict__ gamma, const float* __restrict__ beta,
    const float* __restrict__ dis, const int* __restrict__ perm,
    const int* __restrict__ gs,
    float* __restrict__ out)
{
    __shared__ __align__(16) char RA[36864];   // XR | T2 | HB | F
    __shared__ __align__(16) char RB[36864];   // T1+A1 | A2 | T3
    __shared__ __align__(16) float b2s[256];
    __shared__ __align__(16) float b3s[128];
    __shared__ __align__(16) float sd[64];
    __shared__ int sp[64];

    float* XR = (float*)RA;                    // 64 x 128 fp32
    short* T2 = (short*)RA;                    // 256 x 72 bf16 (c-major h1)
    short* HB = (short*)RA;                    // 64 x 264 bf16 (h2)
    float* F  = (float*)RA;                    // 64 x 132 fp32
    short* T1 = (short*)RB;                    // 128 x 72 bf16
    short* A1 = (short*)(RB + 18432);          // 64 x 136 bf16
    short* A2 = (short*)RB;                    // 64 x 264 bf16
    short* T3 = (short*)RB;                    // 128 x 72 bf16

    int tid = threadIdx.x;
    int w = tid >> 6;          // wave 0..7
    int lane = tid & 63;
    int quad = lane >> 4;
    int l15 = lane & 15;

    int g = blockIdx.x;
    int s = gs[g], cnt = gs[g + 1] - s;
    if (cnt <= 0) return;

    if (tid < 256) b2s[tid] = b2[tid];
    if (tid < 128) b3s[tid] = b3[tid];

    float bj1[2];              // GEMM1 bias: wave owns n-tiles 2w..2w+1
#pragma unroll
    for (int nt = 0; nt < 2; ++nt) bj1[nt] = b1[(w * 2 + nt) * 16 + l15];
    float2 gmv = *(const float2*)&gamma[lane * 2];
    float2 btv = *(const float2*)&beta[lane * 2];

    // lower-triangular-ones B-frag generator (verified R7/R9/R13)
    auto ltfrag = [&](int nt, int k2) -> short8 {
        int thr = nt * 16 + l15 - k2 * 32 - quad * 8;
        short8 f;
#pragma unroll
        for (int e = 0; e < 8; ++e)
            f[e] = (e <= thr) ? (short)0x3F80 : (short)0;
        return f;
    };

    float c1[4], c2[2][4], c3[4];
#pragma unroll
    for (int r = 0; r < 4; ++r) {
        c1[r] = 0.f; c3[r] = 0.f;
        c2[0][r] = 0.f; c2[1][r] = 0.f;
    }

    // chunk-loop-opaque weight pointers (LICM breaker)
    const short* wt1p = (const short*)Wt1_;
    const short* wt2p = (const short*)Wt2_;
    const short* wt3p = (const short*)Wt3_;

    for (int base = 0; base < cnt; base += 64) {
        // Redefine pointers each iteration: empty asm makes their values
        // loop-carried-opaque so weight loads cannot be hoisted out of the
        // loop (R13: hoisting consumed 128 VGPRs -> cap -> 19 MB spill).
        asm("" : "+s"(wt1p), "+s"(wt2p), "+s"(wt3p));

        int mt = min(64, cnt - base);
        __syncthreads();   // prev chunk LN done with F/sp
        if (tid < 64) {
            int p = (tid < mt) ? perm[s + base + tid] : perm[s];
            sp[tid] = p;
            sd[tid] = (tid < mt) ? dis[p] : 0.0f;
        }
        __syncthreads();

        float djn[4];
#pragma unroll
        for (int nt = 0; nt < 4; ++nt) djn[nt] = sd[nt * 16 + l15];

        // ---- stage x: DMA 64 rows of x -> XR; wave w owns rows 8w..8w+7 ----
        {
            int r0 = 8 * w;
#pragma unroll
            for (int ii = 0; ii < 4; ++ii) {
                int row = r0 + 2 * ii + (lane >> 5);
                const float* src = x + (size_t)sp[row] * D_IN + (lane & 31) * 4;
                gl_lds16(src, &XR[(r0 + 2 * ii) * D_IN]);
            }
        }
        __syncthreads();

        // ---- repack: T1[c][r] = bf16(XR[r][c] * sd[r]); 512 thr, 16 rows ea ----
        {
            int c = tid & 127;
            int q = tid >> 7;   // 0..3
#pragma unroll
            for (int p = 0; p < 2; ++p) {
                int rb = q * 16 + p * 8;
                short8 o;
#pragma unroll
                for (int e = 0; e < 8; ++e)
                    o[e] = f2b(XR[(rb + e) * D_IN + c] * sd[rb + e]);
                *(short8*)&T1[c * ST1 + rb] = o;
            }
        }
        __syncthreads();

        // ---- scan1 (MFMA): A1[j][c] = dj*(c1 + cumsum(T1)); 1 m-tile/wave ----
        {
            floatx4 acc[4];
#pragma unroll
            for (int nt = 0; nt < 4; ++nt) acc[nt] = (floatx4)0.0f;
#pragma unroll
            for (int k2 = 0; k2 < 2; ++k2) {
                short8 af = *(const short8*)&T1[(w * 16 + l15) * ST1 + k2 * 32 + quad * 8];
#pragma unroll
                for (int nt = 0; nt < 4; ++nt)
                    acc[nt] = __builtin_amdgcn_mfma_f32_16x16x32_bf16(
                        af, ltfrag(nt, k2), acc[nt], 0, 0, 0);
            }
            float nc[4] = {0.f, 0.f, 0.f, 0.f};
#pragma unroll
            for (int nt = 0; nt < 4; ++nt) {
                float tmp[4];
#pragma unroll
                for (int r = 0; r < 4; ++r) tmp[r] = acc[nt][r] + c1[r];
                if (nt == 3) {
#pragma unroll
                    for (int r = 0; r < 4; ++r) nc[r] = tmp[r];
                }
                short4v o4;
#pragma unroll
                for (int r = 0; r < 4; ++r) o4[r] = f2b(tmp[r] * djn[nt]);
                *(short4v*)&A1[(nt * 16 + l15) * SA1 + w * 16 + quad * 4] = o4;
            }
#pragma unroll
            for (int r = 0; r < 4; ++r)
                c1[r] = __shfl(nc[r], (lane & 48) + 15);
        }
        __syncthreads();

        // ---- GEMM1: T2[c][j] = relu(A1 @ Wt1^T + b1)*sd[j]; 2 n-tiles/wave ----
        {
            floatx4 acc[4][2];
#pragma unroll
            for (int i = 0; i < 4; ++i)
#pragma unroll
                for (int nt = 0; nt < 2; ++nt) acc[i][nt] = (floatx4)0.0f;
#pragma unroll
            for (int kk = 0; kk < 4; ++kk) {   // K = 128
                short8 af[4], bf[2];
#pragma unroll
                for (int i = 0; i < 4; ++i)
                    af[i] = *(const short8*)&A1[(i * 16 + l15) * SA1 + kk * 32 + quad * 8];
#pragma unroll
                for (int nt = 0; nt < 2; ++nt)
                    bf[nt] = *(const short8*)&wt1p[((size_t)(w * 2 + nt) * 16 + l15) * D_IN + kk * 32 + quad * 8];
#pragma unroll
                for (int i = 0; i < 4; ++i)
#pragma unroll
                    for (int nt = 0; nt < 2; ++nt)
                        acc[i][nt] = __builtin_amdgcn_mfma_f32_16x16x32_bf16(
                            af[i], bf[nt], acc[i][nt], 0, 0, 0);
            }
#pragma unroll
            for (int i = 0; i < 4; ++i) {
                float4 sdv = *(const float4*)&sd[i * 16 + quad * 4];   // sd[j]
#pragma unroll
                for (int nt = 0; nt < 2; ++nt) {
                    short4v o4;
                    o4[0] = f2b(fmaxf(acc[i][nt][0] + bj1[nt], 0.0f) * sdv.x);
                    o4[1] = f2b(fmaxf(acc[i][nt][1] + bj1[nt], 0.0f) * sdv.y);
                    o4[2] = f2b(fmaxf(acc[i][nt][2] + bj1[nt], 0.0f) * sdv.z);
                    o4[3] = f2b(fmaxf(acc[i][nt][3] + bj1[nt], 0.0f) * sdv.w);
                    *(short4v*)&T2[((w * 2 + nt) * 16 + l15) * ST2 + i * 16 + quad * 4] = o4;
                }
            }
        }
        __syncthreads();

        // ---- scan2 (MFMA): A2[j][c] = dj*(c2 + cumsum(T2)); 2 m-tiles/wave ----
        {
            floatx4 acc[2][4];
#pragma unroll
            for (int i = 0; i < 2; ++i)
#pragma unroll
                for (int nt = 0; nt < 4; ++nt) acc[i][nt] = (floatx4)0.0f;
#pragma unroll
            for (int k2 = 0; k2 < 2; ++k2) {
                short8 af[2];
#pragma unroll
                for (int i = 0; i < 2; ++i)
                    af[i] = *(const short8*)&T2[((2 * w + i) * 16 + l15) * ST2 + k2 * 32 + quad * 8];
#pragma unroll
                for (int nt = 0; nt < 4; ++nt) {
                    short8 lt = ltfrag(nt, k2);
#pragma unroll
                    for (int i = 0; i < 2; ++i)
                        acc[i][nt] = __builtin_amdgcn_mfma_f32_16x16x32_bf16(
                            af[i], lt, acc[i][nt], 0, 0, 0);
                }
            }
#pragma unroll
            for (int i = 0; i < 2; ++i) {
                float nc[4] = {0.f, 0.f, 0.f, 0.f};
#pragma unroll
                for (int nt = 0; nt < 4; ++nt) {
                    float tmp[4];
#pragma unroll
                    for (int r = 0; r < 4; ++r) tmp[r] = acc[i][nt][r] + c2[i][r];
                    if (nt == 3) {
#pragma unroll
                        for (int r = 0; r < 4; ++r) nc[r] = tmp[r];
                    }
                    short4v o4;
#pragma unroll
                    for (int r = 0; r < 4; ++r) o4[r] = f2b(tmp[r] * djn[nt]);
                    *(short4v*)&A2[(nt * 16 + l15) * SA2 + (2 * w + i) * 16 + quad * 4] = o4;
                }
#pragma unroll
                for (int r = 0; r < 4; ++r)
                    c2[i][r] = __shfl(nc[r], (lane & 48) + 15);
            }
        }
        __syncthreads();

        // ---- GEMM2: HB[j][c2] = relu(A2 @ Wt2^T + b2); 2 m-tiles/wave ----
        {
            floatx4 acc[2][4];
#pragma unroll
            for (int i = 0; i < 2; ++i)
#pragma unroll
                for (int nt = 0; nt < 4; ++nt) acc[i][nt] = (floatx4)0.0f;
#pragma unroll
            for (int kk = 0; kk < 8; ++kk) {   // K = 256
                short8 af[2], bf[4];
#pragma unroll
                for (int i = 0; i < 2; ++i)
                    af[i] = *(const short8*)&wt2p[((size_t)(2 * w + i) * 16 + l15) * H1 + kk * 32 + quad * 8];
#pragma unroll
                for (int nt = 0; nt < 4; ++nt)
                    bf[nt] = *(const short8*)&A2[(nt * 16 + l15) * SA2 + kk * 32 + quad * 8];
#pragma unroll
                for (int i = 0; i < 2; ++i)
#pragma unroll
                    for (int nt = 0; nt < 4; ++nt)
                        acc[i][nt] = __builtin_amdgcn_mfma_f32_16x16x32_bf16(
                            af[i], bf[nt], acc[i][nt], 0, 0, 0);
            }
#pragma unroll
            for (int i = 0; i < 2; ++i) {
                float4 bb = *(const float4*)&b2s[(2 * w + i) * 16 + quad * 4];
#pragma unroll
                for (int nt = 0; nt < 4; ++nt) {
                    short4v o4;
                    o4[0] = f2b(fmaxf(acc[i][nt][0] + bb.x, 0.0f));
                    o4[1] = f2b(fmaxf(acc[i][nt][1] + bb.y, 0.0f));
                    o4[2] = f2b(fmaxf(acc[i][nt][2] + bb.z, 0.0f));
                    o4[3] = f2b(fmaxf(acc[i][nt][3] + bb.w, 0.0f));
                    *(short4v*)&HB[(nt * 16 + l15) * SH2 + (2 * w + i) * 16 + quad * 4] = o4;
                }
            }
        }
        __syncthreads();

        // ---- GEMM3: T3[d][j] = (HB @ Wt3^T)[j][d]*sd[j]; 1 n-tile/wave ----
        {
            floatx4 acc[4];
#pragma unroll
            for (int i = 0; i < 4; ++i) acc[i] = (floatx4)0.0f;
#pragma unroll
            for (int kk = 0; kk < 8; ++kk) {   // K = 256
                short8 bf = *(const short8*)&wt3p[((size_t)w * 16 + l15) * H2 + kk * 32 + quad * 8];
#pragma unroll
                for (int i = 0; i < 4; ++i) {
                    short8 af = *(const short8*)&HB[(i * 16 + l15) * SH2 + kk * 32 + quad * 8];
                    acc[i] = __builtin_amdgcn_mfma_f32_16x16x32_bf16(
                        af, bf, acc[i], 0, 0, 0);
                }
            }
#pragma unroll
            for (int i = 0; i < 4; ++i) {
                float4 sdv = *(const float4*)&sd[i * 16 + quad * 4];
                short4v o4;
                o4[0] = f2b(acc[i][0] * sdv.x);
                o4[1] = f2b(acc[i][1] * sdv.y);
                o4[2] = f2b(acc[i][2] * sdv.z);
                o4[3] = f2b(acc[i][3] * sdv.w);
                *(short4v*)&T3[(w * 16 + l15) * ST3 + i * 16 + quad * 4] = o4;
            }
        }
        __syncthreads();

        // ---- scan3 (MFMA): F[j][d] = relu(dj*(c3+cumsum(T3))+b3); 1 m-tile/wave
        {
            floatx4 acc[4];
#pragma unroll
            for (int nt = 0; nt < 4; ++nt) acc[nt] = (floatx4)0.0f;
#pragma unroll
            for (int k2 = 0; k2 < 2; ++k2) {
                short8 af = *(const short8*)&T3[(w * 16 + l15) * ST3 + k2 * 32 + quad * 8];
#pragma unroll
                for (int nt = 0; nt < 4; ++nt)
                    acc[nt] = __builtin_amdgcn_mfma_f32_16x16x32_bf16(
                        af, ltfrag(nt, k2), acc[nt], 0, 0, 0);
            }
            float4 bb = *(const float4*)&b3s[w * 16 + quad * 4];
            float nc[4] = {0.f, 0.f, 0.f, 0.f};
#pragma unroll
            for (int nt = 0; nt < 4; ++nt) {
                float tmp[4];
#pragma unroll
                for (int r = 0; r < 4; ++r) tmp[r] = acc[nt][r] + c3[r];
                if (nt == 3) {
#pragma unroll
                    for (int r = 0; r < 4; ++r) nc[r] = tmp[r];
                }
                float4 o;
                o.x = fmaxf(tmp[0] * djn[nt] + bb.x, 0.0f);
                o.y = fmaxf(tmp[1] * djn[nt] + bb.y, 0.0f);
                o.z = fmaxf(tmp[2] * djn[nt] + bb.z, 0.0f);
                o.w = fmaxf(tmp[3] * djn[nt] + bb.w, 0.0f);
                *(float4*)&F[(nt * 16 + l15) * SF + w * 16 + quad * 4] = o;
            }
#pragma unroll
            for (int r = 0; r < 4; ++r)
                c3[r] = __shfl(nc[r], (lane & 48) + 15);
        }
        __syncthreads();

        // ---- LayerNorm rows -> out (8 waves: rows w, w+8, ...) ----
        for (int r = w; r < mt; r += 8) {
            float2 v = *(const float2*)&F[r * SF + lane * 2];
            float s1 = v.x + v.y;
            float s2v = v.x * v.x + v.y * v.y;
#pragma unroll
            for (int off = 32; off > 0; off >>= 1) {
                s1 += __shfl_down(s1, off);
                s2v += __shfl_down(s2v, off);
            }
            s1 = __shfl(s1, 0);
            s2v = __shfl(s2v, 0);
            float mu = s1 * (1.0f / D_OUT);
            float var = s2v * (1.0f / D_OUT) - mu * mu;
            float rstd = rsqrtf(var + 1e-5f);
            float2 o;
            o.x = (v.x - mu) * rstd * gmv.x + btv.x;
            o.y = (v.y - mu) * rstd * gmv.y + btv.y;
            *(float2*)&out[(size_t)sp[r] * D_OUT + lane * 2] = o;
        }
    }
}

// ---------------------------------------------------------------------------

extern "C" void kernel_launch(void* const* d_in, const int* in_sizes, int n_in,
                              void* d_out, int out_size, void* d_ws, size_t ws_size,
                              hipStream_t stream) {
    const float* x     = (const float*)d_in[0];
    const int*   idx   = (const int*)d_in[1];
    const float* W1    = (const float*)d_in[2];
    const float* b1    = (const float*)d_in[3];
    const float* W2    = (const float*)d_in[4];
    const float* b2    = (const float*)d_in[5];
    const float* W3    = (const float*)d_in[6];
    const float* b3    = (const float*)d_in[7];
    const float* gamma = (const float*)d_in[8];
    const float* beta  = (const float*)d_in[9];
    float* out = (float*)d_out;

    char* ws = (char*)d_ws;
    size_t off = 0;
    auto alloc = [&](size_t bytes) -> void* {
        void* p = (void*)(ws + off);
        off += (bytes + 255) & ~(size_t)255;
        return p;
    };
    float* dis   = (float*)alloc(NN * sizeof(float));
    int*   perm  = (int*)alloc(NN * sizeof(int));
    int*   lrank = (int*)alloc(NN * sizeof(int));
    int*   gs    = (int*)alloc((NG + 1) * sizeof(int));
    int*   bhist = (int*)alloc(NG * NB_PAD * sizeof(int));
    int*   boff  = (int*)alloc(NG * NB_PAD * sizeof(int));
    __hip_bfloat16* Wt1 = (__hip_bfloat16*)alloc((size_t)D_IN * H1 * 2);
    __hip_bfloat16* Wt2 = (__hip_bfloat16*)alloc((size_t)H1 * H2 * 2);
    __hip_bfloat16* Wt3 = (__hip_bfloat16*)alloc((size_t)H2 * D_OUT * 2);

    rank1_kernel<<<NB_RANK, 256, 0, stream>>>(idx, lrank, bhist);
    rank2_kernel<<<1, 512, 0, stream>>>(bhist, boff, gs);
    rank3_kernel<<<NB_RANK, 256, 0, stream>>>(idx, lrank, boff, gs, dis, perm);
    wt_all<<<(WT_ELEMS + 255) / 256, 256, 0, stream>>>(
        W1, W2, W3, Wt1, Wt2, Wt3);

    fused_gcn<<<NG, 512, 0, stream>>>(
        x, Wt1, Wt2, Wt3, b1, b2, b3, gamma, beta, dis, perm, gs, out);
}

// Round 15
// 132.065 us; speedup vs baseline: 1.3552x; 1.0721x over previous
//
#include <hip/hip_runtime.h>
#include <hip/hip_bf16.h>

// Problem constants (GCN_66649302499531)
#define NN 20000
#define NG 400
#define D_IN 128
#define H1 256
#define H2 256
#define D_OUT 128
#define WT_ELEMS (D_IN * H1 + H1 * H2 + H2 * D_OUT)   // 131072
#define MCAP 1024   // member-list cap: mean group 50, sigma ~7 -> 1024 is 138 sigma

typedef __attribute__((ext_vector_type(8))) short short8;
typedef __attribute__((ext_vector_type(4))) short short4v;
typedef __attribute__((ext_vector_type(4))) float floatx4;

__device__ __forceinline__ short f2b(float f) {
    __hip_bfloat16 h = __float2bfloat16(f);
    return *(short*)&h;
}

// async global->LDS DMA, 16B/lane: per-lane global addr, wave-uniform LDS base.
// Only used from fully-unrolled loops (rolled-loop usage miscompiled in R11).
__device__ __forceinline__ void gl_lds16(const void* g, void* l) {
    __builtin_amdgcn_global_load_lds(
        (__attribute__((address_space(1))) void*)g,
        (__attribute__((address_space(3))) void*)l, 16, 0, 0);
}

// ---------------------------------------------------------------------------
// Weight transposes fp32 [K][N] -> bf16 [N][K], one launch.
// ---------------------------------------------------------------------------

__global__ __launch_bounds__(256) void wt_all(
    const float* __restrict__ W1, const float* __restrict__ W2,
    const float* __restrict__ W3, __hip_bfloat16* __restrict__ Wt1,
    __hip_bfloat16* __restrict__ Wt2, __hip_bfloat16* __restrict__ Wt3)
{
    int o = blockIdx.x * 256 + threadIdx.x;
    if (o < D_IN * H1) {
        int n = o / D_IN, k = o - n * D_IN;
        Wt1[o] = __float2bfloat16(W1[(size_t)k * H1 + n]);
    } else if (o < D_IN * H1 + H1 * H2) {
        int p = o - D_IN * H1;
        int n = p / H1, k = p - n * H1;
        Wt2[p] = __float2bfloat16(W2[(size_t)k * H2 + n]);
    } else if (o < WT_ELEMS) {
        int p = o - D_IN * H1 - H1 * H2;
        int n = p / H2, k = p - n * H2;
        Wt3[p] = __float2bfloat16(W3[(size_t)k * D_OUT + n]);
    }
}

// ---------------------------------------------------------------------------
// Fused per-group pipeline — R14 structure (8 waves / 512 thr, LICM-broken
// weight pointers, no spill) + SELF-CONTAINED RANK PROLOGUE:
// each block scans idx once (int4 tiles of 2048, ballot-compaction) and
// builds its group's index-ordered member list in LDS. dis for member at
// list position p is rsqrtf(p+1) — no rank kernels, no perm/dis arrays,
// launch count 5 -> 2 (R10: ~5 us per launch gap).
// ---------------------------------------------------------------------------

#define ST1 72
#define SA1 136
#define ST2 72
#define SA2 264
#define SH2 264
#define ST3 72
#define SF 132

__global__ __launch_bounds__(512) void fused_gcn(
    const float* __restrict__ x, const int* __restrict__ idx,
    const __hip_bfloat16* __restrict__ Wt1_,
    const __hip_bfloat16* __restrict__ Wt2_,
    const __hip_bfloat16* __restrict__ Wt3_,
    const float* __restrict__ b1, const float* __restrict__ b2,
    const float* __restrict__ b3,
    const float* __restrict__ gamma, const float* __restrict__ beta,
    float* __restrict__ out)
{
    __shared__ __align__(16) char RA[36864];   // XR | T2 | HB | F
    __shared__ __align__(16) char RB[36864];   // T1+A1 | A2 | T3
    __shared__ __align__(16) float b2s[256];
    __shared__ __align__(16) float b3s[128];
    __shared__ __align__(16) float sd[64];
    __shared__ int sp[64];
    __shared__ int mlist[MCAP];
    __shared__ int wcnt[8];

    float* XR = (float*)RA;                    // 64 x 128 fp32
    short* T2 = (short*)RA;                    // 256 x 72 bf16 (c-major h1)
    short* HB = (short*)RA;                    // 64 x 264 bf16 (h2)
    float* F  = (float*)RA;                    // 64 x 132 fp32
    short* T1 = (short*)RB;                    // 128 x 72 bf16
    short* A1 = (short*)(RB + 18432);          // 64 x 136 bf16
    short* A2 = (short*)RB;                    // 64 x 264 bf16
    short* T3 = (short*)RB;                    // 128 x 72 bf16

    int tid = threadIdx.x;
    int w = tid >> 6;          // wave 0..7
    int lane = tid & 63;
    int quad = lane >> 4;
    int l15 = lane & 15;
    int g = blockIdx.x;

    // ---- prologue: build index-ordered member list of group g ----
    int llen = 0;
    for (int B = 0; B < NN; B += 2048) {
        int j0 = B + 4 * tid;
        int4 v = make_int4(-1, -1, -1, -1);
        if (j0 + 3 < NN) {
            v = *(const int4*)&idx[j0];
        } else {
            if (j0 < NN)     v.x = idx[j0];
            if (j0 + 1 < NN) v.y = idx[j0 + 1];
            if (j0 + 2 < NN) v.z = idx[j0 + 2];
        }
        bool f0 = (v.x == g), f1 = (v.y == g), f2 = (v.z == g), f3 = (v.w == g);
        unsigned long long m0 = __ballot(f0), m1 = __ballot(f1);
        unsigned long long m2 = __ballot(f2), m3 = __ballot(f3);
        unsigned long long lowm = (1ull << lane) - 1ull;
        int p = __popcll(m0 & lowm) + __popcll(m1 & lowm) +
                __popcll(m2 & lowm) + __popcll(m3 & lowm);
        if (lane == 0)
            wcnt[w] = __popcll(m0) + __popcll(m1) + __popcll(m2) + __popcll(m3);
        __syncthreads();
        int wbase = 0, tot = 0;
        for (int ww = 0; ww < 8; ++ww) {
            int c = wcnt[ww];
            if (ww < w) wbase += c;
            tot += c;
        }
        int s0 = llen + wbase + p;
        int e0 = (int)f0, e1 = (int)f1, e2 = (int)f2;
        if (f0 && s0 < MCAP)                mlist[s0] = j0;
        if (f1 && s0 + e0 < MCAP)           mlist[s0 + e0] = j0 + 1;
        if (f2 && s0 + e0 + e1 < MCAP)      mlist[s0 + e0 + e1] = j0 + 2;
        if (f3 && s0 + e0 + e1 + e2 < MCAP) mlist[s0 + e0 + e1 + e2] = j0 + 3;
        llen += tot;
        __syncthreads();   // protect wcnt before next tile's overwrite
    }
    int cnt = min(llen, MCAP);
    if (cnt <= 0) return;

    if (tid < 256) b2s[tid] = b2[tid];
    if (tid < 128) b3s[tid] = b3[tid];

    float bj1[2];              // GEMM1 bias: wave owns n-tiles 2w..2w+1
#pragma unroll
    for (int nt = 0; nt < 2; ++nt) bj1[nt] = b1[(w * 2 + nt) * 16 + l15];
    float2 gmv = *(const float2*)&gamma[lane * 2];
    float2 btv = *(const float2*)&beta[lane * 2];

    // lower-triangular-ones B-frag generator (verified R7/R9/R13/R14)
    auto ltfrag = [&](int nt, int k2) -> short8 {
        int thr = nt * 16 + l15 - k2 * 32 - quad * 8;
        short8 f;
#pragma unroll
        for (int e = 0; e < 8; ++e)
            f[e] = (e <= thr) ? (short)0x3F80 : (short)0;
        return f;
    };

    float c1[4], c2[2][4], c3[4];
#pragma unroll
    for (int r = 0; r < 4; ++r) {
        c1[r] = 0.f; c3[r] = 0.f;
        c2[0][r] = 0.f; c2[1][r] = 0.f;
    }

    // chunk-loop-opaque weight pointers (LICM breaker — R13/R14 evidence)
    const short* wt1p = (const short*)Wt1_;
    const short* wt2p = (const short*)Wt2_;
    const short* wt3p = (const short*)Wt3_;

    for (int base = 0; base < cnt; base += 64) {
        asm("" : "+s"(wt1p), "+s"(wt2p), "+s"(wt3p));

        int mt = min(64, cnt - base);
        __syncthreads();   // prev chunk LN done with F/sp
        if (tid < 64) {
            sp[tid] = (tid < mt) ? mlist[base + tid] : mlist[0];
            sd[tid] = (tid < mt) ? rsqrtf((float)(base + tid + 1)) : 0.0f;
        }
        __syncthreads();

        float djn[4];
#pragma unroll
        for (int nt = 0; nt < 4; ++nt) djn[nt] = sd[nt * 16 + l15];

        // ---- stage x: DMA 64 rows of x -> XR; wave w owns rows 8w..8w+7 ----
        {
            int r0 = 8 * w;
#pragma unroll
            for (int ii = 0; ii < 4; ++ii) {
                int row = r0 + 2 * ii + (lane >> 5);
                const float* src = x + (size_t)sp[row] * D_IN + (lane & 31) * 4;
                gl_lds16(src, &XR[(r0 + 2 * ii) * D_IN]);
            }
        }
        __syncthreads();

        // ---- repack: T1[c][r] = bf16(XR[r][c] * sd[r]) ----
        {
            int c = tid & 127;
            int q = tid >> 7;   // 0..3
#pragma unroll
            for (int p = 0; p < 2; ++p) {
                int rb = q * 16 + p * 8;
                short8 o;
#pragma unroll
                for (int e = 0; e < 8; ++e)
                    o[e] = f2b(XR[(rb + e) * D_IN + c] * sd[rb + e]);
                *(short8*)&T1[c * ST1 + rb] = o;
            }
        }
        __syncthreads();

        // ---- scan1 (MFMA): A1[j][c] = dj*(c1 + cumsum(T1)); 1 m-tile/wave ----
        {
            floatx4 acc[4];
#pragma unroll
            for (int nt = 0; nt < 4; ++nt) acc[nt] = (floatx4)0.0f;
#pragma unroll
            for (int k2 = 0; k2 < 2; ++k2) {
                short8 af = *(const short8*)&T1[(w * 16 + l15) * ST1 + k2 * 32 + quad * 8];
#pragma unroll
                for (int nt = 0; nt < 4; ++nt)
                    acc[nt] = __builtin_amdgcn_mfma_f32_16x16x32_bf16(
                        af, ltfrag(nt, k2), acc[nt], 0, 0, 0);
            }
            float nc[4] = {0.f, 0.f, 0.f, 0.f};
#pragma unroll
            for (int nt = 0; nt < 4; ++nt) {
                float tmp[4];
#pragma unroll
                for (int r = 0; r < 4; ++r) tmp[r] = acc[nt][r] + c1[r];
                if (nt == 3) {
#pragma unroll
                    for (int r = 0; r < 4; ++r) nc[r] = tmp[r];
                }
                short4v o4;
#pragma unroll
                for (int r = 0; r < 4; ++r) o4[r] = f2b(tmp[r] * djn[nt]);
                *(short4v*)&A1[(nt * 16 + l15) * SA1 + w * 16 + quad * 4] = o4;
            }
#pragma unroll
            for (int r = 0; r < 4; ++r)
                c1[r] = __shfl(nc[r], (lane & 48) + 15);
        }
        __syncthreads();

        // ---- GEMM1: T2[c][j] = relu(A1 @ Wt1^T + b1)*sd[j]; 2 n-tiles/wave ----
        {
            floatx4 acc[4][2];
#pragma unroll
            for (int i = 0; i < 4; ++i)
#pragma unroll
                for (int nt = 0; nt < 2; ++nt) acc[i][nt] = (floatx4)0.0f;
#pragma unroll
            for (int kk = 0; kk < 4; ++kk) {   // K = 128
                short8 af[4], bf[2];
#pragma unroll
                for (int i = 0; i < 4; ++i)
                    af[i] = *(const short8*)&A1[(i * 16 + l15) * SA1 + kk * 32 + quad * 8];
#pragma unroll
                for (int nt = 0; nt < 2; ++nt)
                    bf[nt] = *(const short8*)&wt1p[((size_t)(w * 2 + nt) * 16 + l15) * D_IN + kk * 32 + quad * 8];
#pragma unroll
                for (int i = 0; i < 4; ++i)
#pragma unroll
                    for (int nt = 0; nt < 2; ++nt)
                        acc[i][nt] = __builtin_amdgcn_mfma_f32_16x16x32_bf16(
                            af[i], bf[nt], acc[i][nt], 0, 0, 0);
            }
#pragma unroll
            for (int i = 0; i < 4; ++i) {
                float4 sdv = *(const float4*)&sd[i * 16 + quad * 4];   // sd[j]
#pragma unroll
                for (int nt = 0; nt < 2; ++nt) {
                    short4v o4;
                    o4[0] = f2b(fmaxf(acc[i][nt][0] + bj1[nt], 0.0f) * sdv.x);
                    o4[1] = f2b(fmaxf(acc[i][nt][1] + bj1[nt], 0.0f) * sdv.y);
                    o4[2] = f2b(fmaxf(acc[i][nt][2] + bj1[nt], 0.0f) * sdv.z);
                    o4[3] = f2b(fmaxf(acc[i][nt][3] + bj1[nt], 0.0f) * sdv.w);
                    *(short4v*)&T2[((w * 2 + nt) * 16 + l15) * ST2 + i * 16 + quad * 4] = o4;
                }
            }
        }
        __syncthreads();

        // ---- scan2 (MFMA): A2[j][c] = dj*(c2 + cumsum(T2)); 2 m-tiles/wave ----
        {
            floatx4 acc[2][4];
#pragma unroll
            for (int i = 0; i < 2; ++i)
#pragma unroll
                for (int nt = 0; nt < 4; ++nt) acc[i][nt] = (floatx4)0.0f;
#pragma unroll
            for (int k2 = 0; k2 < 2; ++k2) {
                short8 af[2];
#pragma unroll
                for (int i = 0; i < 2; ++i)
                    af[i] = *(const short8*)&T2[((2 * w + i) * 16 + l15) * ST2 + k2 * 32 + quad * 8];
#pragma unroll
                for (int nt = 0; nt < 4; ++nt) {
                    short8 lt = ltfrag(nt, k2);
#pragma unroll
                    for (int i = 0; i < 2; ++i)
                        acc[i][nt] = __builtin_amdgcn_mfma_f32_16x16x32_bf16(
                            af[i], lt, acc[i][nt], 0, 0, 0);
                }
            }
#pragma unroll
            for (int i = 0; i < 2; ++i) {
                float nc[4] = {0.f, 0.f, 0.f, 0.f};
#pragma unroll
                for (int nt = 0; nt < 4; ++nt) {
                    float tmp[4];
#pragma unroll
                    for (int r = 0; r < 4; ++r) tmp[r] = acc[i][nt][r] + c2[i][r];
                    if (nt == 3) {
#pragma unroll
                        for (int r = 0; r < 4; ++r) nc[r] = tmp[r];
                    }
                    short4v o4;
#pragma unroll
                    for (int r = 0; r < 4; ++r) o4[r] = f2b(tmp[r] * djn[nt]);
                    *(short4v*)&A2[(nt * 16 + l15) * SA2 + (2 * w + i) * 16 + quad * 4] = o4;
                }
#pragma unroll
                for (int r = 0; r < 4; ++r)
                    c2[i][r] = __shfl(nc[r], (lane & 48) + 15);
            }
        }
        __syncthreads();

        // ---- GEMM2: HB[j][c2] = relu(A2 @ Wt2^T + b2); 2 m-tiles/wave ----
        {
            floatx4 acc[2][4];
#pragma unroll
            for (int i = 0; i < 2; ++i)
#pragma unroll
                for (int nt = 0; nt < 4; ++nt) acc[i][nt] = (floatx4)0.0f;
#pragma unroll
            for (int kk = 0; kk < 8; ++kk) {   // K = 256
                short8 af[2], bf[4];
#pragma unroll
                for (int i = 0; i < 2; ++i)
                    af[i] = *(const short8*)&wt2p[((size_t)(2 * w + i) * 16 + l15) * H1 + kk * 32 + quad * 8];
#pragma unroll
                for (int nt = 0; nt < 4; ++nt)
                    bf[nt] = *(const short8*)&A2[(nt * 16 + l15) * SA2 + kk * 32 + quad * 8];
#pragma unroll
                for (int i = 0; i < 2; ++i)
#pragma unroll
                    for (int nt = 0; nt < 4; ++nt)
                        acc[i][nt] = __builtin_amdgcn_mfma_f32_16x16x32_bf16(
                            af[i], bf[nt], acc[i][nt], 0, 0, 0);
            }
#pragma unroll
            for (int i = 0; i < 2; ++i) {
                float4 bb = *(const float4*)&b2s[(2 * w + i) * 16 + quad * 4];
#pragma unroll
                for (int nt = 0; nt < 4; ++nt) {
                    short4v o4;
                    o4[0] = f2b(fmaxf(acc[i][nt][0] + bb.x, 0.0f));
                    o4[1] = f2b(fmaxf(acc[i][nt][1] + bb.y, 0.0f));
                    o4[2] = f2b(fmaxf(acc[i][nt][2] + bb.z, 0.0f));
                    o4[3] = f2b(fmaxf(acc[i][nt][3] + bb.w, 0.0f));
                    *(short4v*)&HB[(nt * 16 + l15) * SH2 + (2 * w + i) * 16 + quad * 4] = o4;
                }
            }
        }
        __syncthreads();

        // ---- GEMM3: T3[d][j] = (HB @ Wt3^T)[j][d]*sd[j]; 1 n-tile/wave ----
        {
            floatx4 acc[4];
#pragma unroll
            for (int i = 0; i < 4; ++i) acc[i] = (floatx4)0.0f;
#pragma unroll
            for (int kk = 0; kk < 8; ++kk) {   // K = 256
                short8 bf = *(const short8*)&wt3p[((size_t)w * 16 + l15) * H2 + kk * 32 + quad * 8];
#pragma unroll
                for (int i = 0; i < 4; ++i) {
                    short8 af = *(const short8*)&HB[(i * 16 + l15) * SH2 + kk * 32 + quad * 8];
                    acc[i] = __builtin_amdgcn_mfma_f32_16x16x32_bf16(
                        af, bf, acc[i], 0, 0, 0);
                }
            }
#pragma unroll
            for (int i = 0; i < 4; ++i) {
                float4 sdv = *(const float4*)&sd[i * 16 + quad * 4];
                short4v o4;
                o4[0] = f2b(acc[i][0] * sdv.x);
                o4[1] = f2b(acc[i][1] * sdv.y);
                o4[2] = f2b(acc[i][2] * sdv.z);
                o4[3] = f2b(acc[i][3] * sdv.w);
                *(short4v*)&T3[(w * 16 + l15) * ST3 + i * 16 + quad * 4] = o4;
            }
        }
        __syncthreads();

        // ---- scan3 (MFMA): F[j][d] = relu(dj*(c3+cumsum(T3))+b3); 1 m-tile/wave
        {
            floatx4 acc[4];
#pragma unroll
            for (int nt = 0; nt < 4; ++nt) acc[nt] = (floatx4)0.0f;
#pragma unroll
            for (int k2 = 0; k2 < 2; ++k2) {
                short8 af = *(const short8*)&T3[(w * 16 + l15) * ST3 + k2 * 32 + quad * 8];
#pragma unroll
                for (int nt = 0; nt < 4; ++nt)
                    acc[nt] = __builtin_amdgcn_mfma_f32_16x16x32_bf16(
                        af, ltfrag(nt, k2), acc[nt], 0, 0, 0);
            }
            float4 bb = *(const float4*)&b3s[w * 16 + quad * 4];
            float nc[4] = {0.f, 0.f, 0.f, 0.f};
#pragma unroll
            for (int nt = 0; nt < 4; ++nt) {
                float tmp[4];
#pragma unroll
                for (int r = 0; r < 4; ++r) tmp[r] = acc[nt][r] + c3[r];
                if (nt == 3) {
#pragma unroll
                    for (int r = 0; r < 4; ++r) nc[r] = tmp[r];
                }
                float4 o;
                o.x = fmaxf(tmp[0] * djn[nt] + bb.x, 0.0f);
                o.y = fmaxf(tmp[1] * djn[nt] + bb.y, 0.0f);
                o.z = fmaxf(tmp[2] * djn[nt] + bb.z, 0.0f);
                o.w = fmaxf(tmp[3] * djn[nt] + bb.w, 0.0f);
                *(float4*)&F[(nt * 16 + l15) * SF + w * 16 + quad * 4] = o;
            }
#pragma unroll
            for (int r = 0; r < 4; ++r)
                c3[r] = __shfl(nc[r], (lane & 48) + 15);
        }
        __syncthreads();

        // ---- LayerNorm rows -> out (8 waves: rows w, w+8, ...) ----
        for (int r = w; r < mt; r += 8) {
            float2 v = *(const float2*)&F[r * SF + lane * 2];
            float s1 = v.x + v.y;
            float s2v = v.x * v.x + v.y * v.y;
#pragma unroll
            for (int off = 32; off > 0; off >>= 1) {
                s1 += __shfl_down(s1, off);
                s2v += __shfl_down(s2v, off);
            }
            s1 = __shfl(s1, 0);
            s2v = __shfl(s2v, 0);
            float mu = s1 * (1.0f / D_OUT);
            float var = s2v * (1.0f / D_OUT) - mu * mu;
            float rstd = rsqrtf(var + 1e-5f);
            float2 o;
            o.x = (v.x - mu) * rstd * gmv.x + btv.x;
            o.y = (v.y - mu) * rstd * gmv.y + btv.y;
            *(float2*)&out[(size_t)sp[r] * D_OUT + lane * 2] = o;
        }
    }
}

// ---------------------------------------------------------------------------

extern "C" void kernel_launch(void* const* d_in, const int* in_sizes, int n_in,
                              void* d_out, int out_size, void* d_ws, size_t ws_size,
                              hipStream_t stream) {
    const float* x     = (const float*)d_in[0];
    const int*   idx   = (const int*)d_in[1];
    const float* W1    = (const float*)d_in[2];
    const float* b1    = (const float*)d_in[3];
    const float* W2    = (const float*)d_in[4];
    const float* b2    = (const float*)d_in[5];
    const float* W3    = (const float*)d_in[6];
    const float* b3    = (const float*)d_in[7];
    const float* gamma = (const float*)d_in[8];
    const float* beta  = (const float*)d_in[9];
    float* out = (float*)d_out;

    char* ws = (char*)d_ws;
    size_t off = 0;
    auto alloc = [&](size_t bytes) -> void* {
        void* p = (void*)(ws + off);
        off += (bytes + 255) & ~(size_t)255;
        return p;
    };
    __hip_bfloat16* Wt1 = (__hip_bfloat16*)alloc((size_t)D_IN * H1 * 2);
    __hip_bfloat16* Wt2 = (__hip_bfloat16*)alloc((size_t)H1 * H2 * 2);
    __hip_bfloat16* Wt3 = (__hip_bfloat16*)alloc((size_t)H2 * D_OUT * 2);

    wt_all<<<(WT_ELEMS + 255) / 256, 256, 0, stream>>>(
        W1, W2, W3, Wt1, Wt2, Wt3);

    fused_gcn<<<NG, 512, 0, stream>>>(
        x, idx, Wt1, Wt2, Wt3, b1, b2, b3, gamma, beta, out);
}

// Round 16
// 127.109 us; speedup vs baseline: 1.4080x; 1.0390x over previous
//
#include <hip/hip_runtime.h>
#include <hip/hip_bf16.h>

// Problem constants (GCN_66649302499531)
#define NN 20000
#define NG 400
#define D_IN 128
#define H1 256
#define H2 256
#define D_OUT 128
#define WT_ELEMS (D_IN * H1 + H1 * H2 + H2 * D_OUT)   // 131072
#define MCAP 1024   // member-list cap (mean group 50; astronomically safe)
#define WSLOT 256   // per-wave slice scratch cap (slice mean 6.25)

typedef __attribute__((ext_vector_type(8))) short short8;
typedef __attribute__((ext_vector_type(4))) short short4v;
typedef __attribute__((ext_vector_type(4))) float floatx4;

__device__ __forceinline__ short f2b(float f) {
    __hip_bfloat16 h = __float2bfloat16(f);
    return *(short*)&h;
}

// async global->LDS DMA, 16B/lane: per-lane global addr, wave-uniform LDS base.
// Only used from fully-unrolled loops (rolled-loop usage miscompiled in R11).
__device__ __forceinline__ void gl_lds16(const void* g, void* l) {
    __builtin_amdgcn_global_load_lds(
        (__attribute__((address_space(1))) void*)g,
        (__attribute__((address_space(3))) void*)l, 16, 0, 0);
}

// ---------------------------------------------------------------------------
// Weight transposes fp32 [K][N] -> bf16 [N][K], one launch.
// ---------------------------------------------------------------------------

__global__ __launch_bounds__(256) void wt_all(
    const float* __restrict__ W1, const float* __restrict__ W2,
    const float* __restrict__ W3, __hip_bfloat16* __restrict__ Wt1,
    __hip_bfloat16* __restrict__ Wt2, __hip_bfloat16* __restrict__ Wt3)
{
    int o = blockIdx.x * 256 + threadIdx.x;
    if (o < D_IN * H1) {
        int n = o / D_IN, k = o - n * D_IN;
        Wt1[o] = __float2bfloat16(W1[(size_t)k * H1 + n]);
    } else if (o < D_IN * H1 + H1 * H2) {
        int p = o - D_IN * H1;
        int n = p / H1, k = p - n * H1;
        Wt2[p] = __float2bfloat16(W2[(size_t)k * H2 + n]);
    } else if (o < WT_ELEMS) {
        int p = o - D_IN * H1 - H1 * H2;
        int n = p / H2, k = p - n * H2;
        Wt3[p] = __float2bfloat16(W3[(size_t)k * D_OUT + n]);
    }
}

// ---------------------------------------------------------------------------
// Fused per-group pipeline — R15 with a WAVE-PARALLEL prologue:
// each wave scans a 2500-node idx slice barrier-free (ballot compaction into
// private LDS scratch aliasing XR), then 1 barrier + 8-count prefix + copy.
// R15's tile-serial prologue cost 11.5 us (20 barriers + serial LDS chains);
// this is ~2 barriers total.
// ---------------------------------------------------------------------------

#define ST1 72
#define SA1 136
#define ST2 72
#define SA2 264
#define SH2 264
#define ST3 72
#define SF 132

__global__ __launch_bounds__(512) void fused_gcn(
    const float* __restrict__ x, const int* __restrict__ idx,
    const __hip_bfloat16* __restrict__ Wt1_,
    const __hip_bfloat16* __restrict__ Wt2_,
    const __hip_bfloat16* __restrict__ Wt3_,
    const float* __restrict__ b1, const float* __restrict__ b2,
    const float* __restrict__ b3,
    const float* __restrict__ gamma, const float* __restrict__ beta,
    float* __restrict__ out)
{
    __shared__ __align__(16) char RA[36864];   // WS | XR | T2 | HB | F
    __shared__ __align__(16) char RB[36864];   // T1+A1 | A2 | T3
    __shared__ __align__(16) float b2s[256];
    __shared__ __align__(16) float b3s[128];
    __shared__ __align__(16) float sd[64];
    __shared__ int sp[64];
    __shared__ int mlist[MCAP];
    __shared__ int wcnt[8];

    float* XR = (float*)RA;                    // 64 x 128 fp32
    short* T2 = (short*)RA;                    // 256 x 72 bf16 (c-major h1)
    short* HB = (short*)RA;                    // 64 x 264 bf16 (h2)
    float* F  = (float*)RA;                    // 64 x 132 fp32
    short* T1 = (short*)RB;                    // 128 x 72 bf16
    short* A1 = (short*)(RB + 18432);          // 64 x 136 bf16
    short* A2 = (short*)RB;                    // 64 x 264 bf16
    short* T3 = (short*)RB;                    // 128 x 72 bf16

    int tid = threadIdx.x;
    int w = tid >> 6;          // wave 0..7
    int lane = tid & 63;
    int quad = lane >> 4;
    int l15 = lane & 15;
    int g = blockIdx.x;

    // ---- prologue: wave-parallel ordered compaction of group g ----
    // wave w scans int4 indices [w*625, (w+1)*625) == nodes [w*2500, ...).
    // Matches land (index-ordered) in WS[w*WSLOT..]; zero barriers in-scan.
    int* WS = (int*)RA;   // aliases XR — dead until chunk 0's DMA
    {
        int slice = w * 625;
        int wcount = 0;
        unsigned long long lowm = (1ull << lane) - 1ull;
#pragma unroll
        for (int b2i = 0; b2i < 2; ++b2i) {
            int4 v[5];
#pragma unroll
            for (int r = 0; r < 5; ++r) {
                int q = (b2i * 5 + r) * 64 + lane;
                v[r] = (q < 625) ? *(const int4*)&idx[(slice + q) * 4]
                                 : make_int4(-1, -1, -1, -1);
            }
#pragma unroll
            for (int r = 0; r < 5; ++r) {
                bool f0 = (v[r].x == g), f1 = (v[r].y == g);
                bool f2 = (v[r].z == g), f3 = (v[r].w == g);
                unsigned long long m0 = __ballot(f0), m1 = __ballot(f1);
                unsigned long long m2 = __ballot(f2), m3 = __ballot(f3);
                int p = wcount + __popcll(m0 & lowm) + __popcll(m1 & lowm)
                               + __popcll(m2 & lowm) + __popcll(m3 & lowm);
                int j0 = (slice + (b2i * 5 + r) * 64 + lane) * 4;
                int e0 = (int)f0, e1 = (int)f1, e2 = (int)f2;
                if (f0 && p < WSLOT)                WS[w * WSLOT + p] = j0;
                if (f1 && p + e0 < WSLOT)           WS[w * WSLOT + p + e0] = j0 + 1;
                if (f2 && p + e0 + e1 < WSLOT)      WS[w * WSLOT + p + e0 + e1] = j0 + 2;
                if (f3 && p + e0 + e1 + e2 < WSLOT) WS[w * WSLOT + p + e0 + e1 + e2] = j0 + 3;
                wcount += __popcll(m0) + __popcll(m1) + __popcll(m2) + __popcll(m3);
            }
        }
        if (lane == 0) wcnt[w] = min(wcount, WSLOT);
    }
    __syncthreads();
    int cnt = 0;
    {
        int myprefix = 0;
#pragma unroll
        for (int ww = 0; ww < 8; ++ww) {
            int c = wcnt[ww];
            if (ww < w) myprefix += c;
            cnt += c;
        }
        cnt = min(cnt, MCAP);
        int myc = wcnt[w];
        for (int k = lane; k < myc; k += 64) {
            int dstp = myprefix + k;
            if (dstp < MCAP) mlist[dstp] = WS[w * WSLOT + k];
        }
        // mlist reads happen after the chunk-top barrier; WS reads above are
        // ordered before XR's DMA overwrite by the same barriers.
    }
    if (cnt <= 0) return;

    if (tid < 256) b2s[tid] = b2[tid];
    if (tid < 128) b3s[tid] = b3[tid];

    float bj1[2];              // GEMM1 bias: wave owns n-tiles 2w..2w+1
#pragma unroll
    for (int nt = 0; nt < 2; ++nt) bj1[nt] = b1[(w * 2 + nt) * 16 + l15];
    float2 gmv = *(const float2*)&gamma[lane * 2];
    float2 btv = *(const float2*)&beta[lane * 2];

    // lower-triangular-ones B-frag generator (verified R7/R9/R13-R15)
    auto ltfrag = [&](int nt, int k2) -> short8 {
        int thr = nt * 16 + l15 - k2 * 32 - quad * 8;
        short8 f;
#pragma unroll
        for (int e = 0; e < 8; ++e)
            f[e] = (e <= thr) ? (short)0x3F80 : (short)0;
        return f;
    };

    float c1[4], c2[2][4], c3[4];
#pragma unroll
    for (int r = 0; r < 4; ++r) {
        c1[r] = 0.f; c3[r] = 0.f;
        c2[0][r] = 0.f; c2[1][r] = 0.f;
    }

    // chunk-loop-opaque weight pointers (LICM breaker — R13/R14 evidence)
    const short* wt1p = (const short*)Wt1_;
    const short* wt2p = (const short*)Wt2_;
    const short* wt3p = (const short*)Wt3_;

    for (int base = 0; base < cnt; base += 64) {
        asm("" : "+s"(wt1p), "+s"(wt2p), "+s"(wt3p));

        int mt = min(64, cnt - base);
        __syncthreads();   // prev chunk LN done with F/sp; also orders mlist
        if (tid < 64) {
            sp[tid] = (tid < mt) ? mlist[base + tid] : mlist[0];
            sd[tid] = (tid < mt) ? rsqrtf((float)(base + tid + 1)) : 0.0f;
        }
        __syncthreads();

        float djn[4];
#pragma unroll
        for (int nt = 0; nt < 4; ++nt) djn[nt] = sd[nt * 16 + l15];

        // ---- stage x: DMA 64 rows of x -> XR; wave w owns rows 8w..8w+7 ----
        {
            int r0 = 8 * w;
#pragma unroll
            for (int ii = 0; ii < 4; ++ii) {
                int row = r0 + 2 * ii + (lane >> 5);
                const float* src = x + (size_t)sp[row] * D_IN + (lane & 31) * 4;
                gl_lds16(src, &XR[(r0 + 2 * ii) * D_IN]);
            }
        }
        __syncthreads();

        // ---- repack: T1[c][r] = bf16(XR[r][c] * sd[r]) ----
        {
            int c = tid & 127;
            int q = tid >> 7;   // 0..3
#pragma unroll
            for (int p = 0; p < 2; ++p) {
                int rb = q * 16 + p * 8;
                short8 o;
#pragma unroll
                for (int e = 0; e < 8; ++e)
                    o[e] = f2b(XR[(rb + e) * D_IN + c] * sd[rb + e]);
                *(short8*)&T1[c * ST1 + rb] = o;
            }
        }
        __syncthreads();

        // ---- scan1 (MFMA): A1[j][c] = dj*(c1 + cumsum(T1)); 1 m-tile/wave ----
        {
            floatx4 acc[4];
#pragma unroll
            for (int nt = 0; nt < 4; ++nt) acc[nt] = (floatx4)0.0f;
#pragma unroll
            for (int k2 = 0; k2 < 2; ++k2) {
                short8 af = *(const short8*)&T1[(w * 16 + l15) * ST1 + k2 * 32 + quad * 8];
#pragma unroll
                for (int nt = 0; nt < 4; ++nt)
                    acc[nt] = __builtin_amdgcn_mfma_f32_16x16x32_bf16(
                        af, ltfrag(nt, k2), acc[nt], 0, 0, 0);
            }
            float nc[4] = {0.f, 0.f, 0.f, 0.f};
#pragma unroll
            for (int nt = 0; nt < 4; ++nt) {
                float tmp[4];
#pragma unroll
                for (int r = 0; r < 4; ++r) tmp[r] = acc[nt][r] + c1[r];
                if (nt == 3) {
#pragma unroll
                    for (int r = 0; r < 4; ++r) nc[r] = tmp[r];
                }
                short4v o4;
#pragma unroll
                for (int r = 0; r < 4; ++r) o4[r] = f2b(tmp[r] * djn[nt]);
                *(short4v*)&A1[(nt * 16 + l15) * SA1 + w * 16 + quad * 4] = o4;
            }
#pragma unroll
            for (int r = 0; r < 4; ++r)
                c1[r] = __shfl(nc[r], (lane & 48) + 15);
        }
        __syncthreads();

        // ---- GEMM1: T2[c][j] = relu(A1 @ Wt1^T + b1)*sd[j]; 2 n-tiles/wave ----
        {
            floatx4 acc[4][2];
#pragma unroll
            for (int i = 0; i < 4; ++i)
#pragma unroll
                for (int nt = 0; nt < 2; ++nt) acc[i][nt] = (floatx4)0.0f;
#pragma unroll
            for (int kk = 0; kk < 4; ++kk) {   // K = 128
                short8 af[4], bf[2];
#pragma unroll
                for (int i = 0; i < 4; ++i)
                    af[i] = *(const short8*)&A1[(i * 16 + l15) * SA1 + kk * 32 + quad * 8];
#pragma unroll
                for (int nt = 0; nt < 2; ++nt)
                    bf[nt] = *(const short8*)&wt1p[((size_t)(w * 2 + nt) * 16 + l15) * D_IN + kk * 32 + quad * 8];
#pragma unroll
                for (int i = 0; i < 4; ++i)
#pragma unroll
                    for (int nt = 0; nt < 2; ++nt)
                        acc[i][nt] = __builtin_amdgcn_mfma_f32_16x16x32_bf16(
                            af[i], bf[nt], acc[i][nt], 0, 0, 0);
            }
#pragma unroll
            for (int i = 0; i < 4; ++i) {
                float4 sdv = *(const float4*)&sd[i * 16 + quad * 4];   // sd[j]
#pragma unroll
                for (int nt = 0; nt < 2; ++nt) {
                    short4v o4;
                    o4[0] = f2b(fmaxf(acc[i][nt][0] + bj1[nt], 0.0f) * sdv.x);
                    o4[1] = f2b(fmaxf(acc[i][nt][1] + bj1[nt], 0.0f) * sdv.y);
                    o4[2] = f2b(fmaxf(acc[i][nt][2] + bj1[nt], 0.0f) * sdv.z);
                    o4[3] = f2b(fmaxf(acc[i][nt][3] + bj1[nt], 0.0f) * sdv.w);
                    *(short4v*)&T2[((w * 2 + nt) * 16 + l15) * ST2 + i * 16 + quad * 4] = o4;
                }
            }
        }
        __syncthreads();

        // ---- scan2 (MFMA): A2[j][c] = dj*(c2 + cumsum(T2)); 2 m-tiles/wave ----
        {
            floatx4 acc[2][4];
#pragma unroll
            for (int i = 0; i < 2; ++i)
#pragma unroll
                for (int nt = 0; nt < 4; ++nt) acc[i][nt] = (floatx4)0.0f;
#pragma unroll
            for (int k2 = 0; k2 < 2; ++k2) {
                short8 af[2];
#pragma unroll
                for (int i = 0; i < 2; ++i)
                    af[i] = *(const short8*)&T2[((2 * w + i) * 16 + l15) * ST2 + k2 * 32 + quad * 8];
#pragma unroll
                for (int nt = 0; nt < 4; ++nt) {
                    short8 lt = ltfrag(nt, k2);
#pragma unroll
                    for (int i = 0; i < 2; ++i)
                        acc[i][nt] = __builtin_amdgcn_mfma_f32_16x16x32_bf16(
                            af[i], lt, acc[i][nt], 0, 0, 0);
                }
            }
#pragma unroll
            for (int i = 0; i < 2; ++i) {
                float nc[4] = {0.f, 0.f, 0.f, 0.f};
#pragma unroll
                for (int nt = 0; nt < 4; ++nt) {
                    float tmp[4];
#pragma unroll
                    for (int r = 0; r < 4; ++r) tmp[r] = acc[i][nt][r] + c2[i][r];
                    if (nt == 3) {
#pragma unroll
                        for (int r = 0; r < 4; ++r) nc[r] = tmp[r];
                    }
                    short4v o4;
#pragma unroll
                    for (int r = 0; r < 4; ++r) o4[r] = f2b(tmp[r] * djn[nt]);
                    *(short4v*)&A2[(nt * 16 + l15) * SA2 + (2 * w + i) * 16 + quad * 4] = o4;
                }
#pragma unroll
                for (int r = 0; r < 4; ++r)
                    c2[i][r] = __shfl(nc[r], (lane & 48) + 15);
            }
        }
        __syncthreads();

        // ---- GEMM2: HB[j][c2] = relu(A2 @ Wt2^T + b2); 2 m-tiles/wave ----
        {
            floatx4 acc[2][4];
#pragma unroll
            for (int i = 0; i < 2; ++i)
#pragma unroll
                for (int nt = 0; nt < 4; ++nt) acc[i][nt] = (floatx4)0.0f;
#pragma unroll
            for (int kk = 0; kk < 8; ++kk) {   // K = 256
                short8 af[2], bf[4];
#pragma unroll
                for (int i = 0; i < 2; ++i)
                    af[i] = *(const short8*)&wt2p[((size_t)(2 * w + i) * 16 + l15) * H1 + kk * 32 + quad * 8];
#pragma unroll
                for (int nt = 0; nt < 4; ++nt)
                    bf[nt] = *(const short8*)&A2[(nt * 16 + l15) * SA2 + kk * 32 + quad * 8];
#pragma unroll
                for (int i = 0; i < 2; ++i)
#pragma unroll
                    for (int nt = 0; nt < 4; ++nt)
                        acc[i][nt] = __builtin_amdgcn_mfma_f32_16x16x32_bf16(
                            af[i], bf[nt], acc[i][nt], 0, 0, 0);
            }
#pragma unroll
            for (int i = 0; i < 2; ++i) {
                float4 bb = *(const float4*)&b2s[(2 * w + i) * 16 + quad * 4];
#pragma unroll
                for (int nt = 0; nt < 4; ++nt) {
                    short4v o4;
                    o4[0] = f2b(fmaxf(acc[i][nt][0] + bb.x, 0.0f));
                    o4[1] = f2b(fmaxf(acc[i][nt][1] + bb.y, 0.0f));
                    o4[2] = f2b(fmaxf(acc[i][nt][2] + bb.z, 0.0f));
                    o4[3] = f2b(fmaxf(acc[i][nt][3] + bb.w, 0.0f));
                    *(short4v*)&HB[(nt * 16 + l15) * SH2 + (2 * w + i) * 16 + quad * 4] = o4;
                }
            }
        }
        __syncthreads();

        // ---- GEMM3: T3[d][j] = (HB @ Wt3^T)[j][d]*sd[j]; 1 n-tile/wave ----
        {
            floatx4 acc[4];
#pragma unroll
            for (int i = 0; i < 4; ++i) acc[i] = (floatx4)0.0f;
#pragma unroll
            for (int kk = 0; kk < 8; ++kk) {   // K = 256
                short8 bf = *(const short8*)&wt3p[((size_t)w * 16 + l15) * H2 + kk * 32 + quad * 8];
#pragma unroll
                for (int i = 0; i < 4; ++i) {
                    short8 af = *(const short8*)&HB[(i * 16 + l15) * SH2 + kk * 32 + quad * 8];
                    acc[i] = __builtin_amdgcn_mfma_f32_16x16x32_bf16(
                        af, bf, acc[i], 0, 0, 0);
                }
            }
#pragma unroll
            for (int i = 0; i < 4; ++i) {
                float4 sdv = *(const float4*)&sd[i * 16 + quad * 4];
                short4v o4;
                o4[0] = f2b(acc[i][0] * sdv.x);
                o4[1] = f2b(acc[i][1] * sdv.y);
                o4[2] = f2b(acc[i][2] * sdv.z);
                o4[3] = f2b(acc[i][3] * sdv.w);
                *(short4v*)&T3[(w * 16 + l15) * ST3 + i * 16 + quad * 4] = o4;
            }
        }
        __syncthreads();

        // ---- scan3 (MFMA): F[j][d] = relu(dj*(c3+cumsum(T3))+b3); 1 m-tile/wave
        {
            floatx4 acc[4];
#pragma unroll
            for (int nt = 0; nt < 4; ++nt) acc[nt] = (floatx4)0.0f;
#pragma unroll
            for (int k2 = 0; k2 < 2; ++k2) {
                short8 af = *(const short8*)&T3[(w * 16 + l15) * ST3 + k2 * 32 + quad * 8];
#pragma unroll
                for (int nt = 0; nt < 4; ++nt)
                    acc[nt] = __builtin_amdgcn_mfma_f32_16x16x32_bf16(
                        af, ltfrag(nt, k2), acc[nt], 0, 0, 0);
            }
            float4 bb = *(const float4*)&b3s[w * 16 + quad * 4];
            float nc[4] = {0.f, 0.f, 0.f, 0.f};
#pragma unroll
            for (int nt = 0; nt < 4; ++nt) {
                float tmp[4];
#pragma unroll
                for (int r = 0; r < 4; ++r) tmp[r] = acc[nt][r] + c3[r];
                if (nt == 3) {
#pragma unroll
                    for (int r = 0; r < 4; ++r) nc[r] = tmp[r];
                }
                float4 o;
                o.x = fmaxf(tmp[0] * djn[nt] + bb.x, 0.0f);
                o.y = fmaxf(tmp[1] * djn[nt] + bb.y, 0.0f);
                o.z = fmaxf(tmp[2] * djn[nt] + bb.z, 0.0f);
                o.w = fmaxf(tmp[3] * djn[nt] + bb.w, 0.0f);
                *(float4*)&F[(nt * 16 + l15) * SF + w * 16 + quad * 4] = o;
            }
#pragma unroll
            for (int r = 0; r < 4; ++r)
                c3[r] = __shfl(nc[r], (lane & 48) + 15);
        }
        __syncthreads();

        // ---- LayerNorm rows -> out (8 waves: rows w, w+8, ...) ----
        for (int r = w; r < mt; r += 8) {
            float2 v = *(const float2*)&F[r * SF + lane * 2];
            float s1 = v.x + v.y;
            float s2v = v.x * v.x + v.y * v.y;
#pragma unroll
            for (int off = 32; off > 0; off >>= 1) {
                s1 += __shfl_down(s1, off);
                s2v += __shfl_down(s2v, off);
            }
            s1 = __shfl(s1, 0);
            s2v = __shfl(s2v, 0);
            float mu = s1 * (1.0f / D_OUT);
            float var = s2v * (1.0f / D_OUT) - mu * mu;
            float rstd = rsqrtf(var + 1e-5f);
            float2 o;
            o.x = (v.x - mu) * rstd * gmv.x + btv.x;
            o.y = (v.y - mu) * rstd * gmv.y + btv.y;
            *(float2*)&out[(size_t)sp[r] * D_OUT + lane * 2] = o;
        }
    }
}

// ---------------------------------------------------------------------------

extern "C" void kernel_launch(void* const* d_in, const int* in_sizes, int n_in,
                              void* d_out, int out_size, void* d_ws, size_t ws_size,
                              hipStream_t stream) {
    const float* x     = (const float*)d_in[0];
    const int*   idx   = (const int*)d_in[1];
    const float* W1    = (const float*)d_in[2];
    const float* b1    = (const float*)d_in[3];
    const float* W2    = (const float*)d_in[4];
    const float* b2    = (const float*)d_in[5];
    const float* W3    = (const float*)d_in[6];
    const float* b3    = (const float*)d_in[7];
    const float* gamma = (const float*)d_in[8];
    const float* beta  = (const float*)d_in[9];
    float* out = (float*)d_out;

    char* ws = (char*)d_ws;
    size_t off = 0;
    auto alloc = [&](size_t bytes) -> void* {
        void* p = (void*)(ws + off);
        off += (bytes + 255) & ~(size_t)255;
        return p;
    };
    __hip_bfloat16* Wt1 = (__hip_bfloat16*)alloc((size_t)D_IN * H1 * 2);
    __hip_bfloat16* Wt2 = (__hip_bfloat16*)alloc((size_t)H1 * H2 * 2);
    __hip_bfloat16* Wt3 = (__hip_bfloat16*)alloc((size_t)H2 * D_OUT * 2);

    wt_all<<<(WT_ELEMS + 255) / 256, 256, 0, stream>>>(
        W1, W2, W3, Wt1, Wt2, Wt3);

    fused_gcn<<<NG, 512, 0, stream>>>(
        x, idx, Wt1, Wt2, Wt3, b1, b2, b3, gamma, beta, out);
}